// Round 10
// baseline (204.083 us; speedup 1.0000x reference)
//
#include <hip/hip_runtime.h>
#include <math.h>

// B=16, C=512, HW=1024.  Chain (per batch):
//   X  (C x HW)  = n1 @ W_c^T
//   E  (HW x HW) = X^T @ n2
//   A  = row-softmax(E)
//   out(C x HW)  = n2 @ A
//
// Round 17 = round 16 (202.7us, best) + A-staging f32 fusion:
//  - gemm1 reads n1 (f32) directly; gemm3 reads n2 (f32) directly. The
//    f32->f16 conversion happens at ds_write time in the staging pipeline
//    (explicit f32x4 prefetch regs keep depth-2 cover; RTN rounding
//    identical to the old prep pass). n1f and n2f buffers DELETED.
//  - prep shrinks to Wc->Wf + n2->n2t (traffic 118MB -> 54MB).
//  - Everything else unchanged from round 16: 512-thread GEMM core
//    (BM=256 BN=128 BK=32, 8 waves, 64x64 wave tiles, both-sides XOR
//    swizzle, depth-2 reg prefetch), gemm2's lean Tt-based stats fusion,
//    exp fused in gemm3 B-staging.
//  - Pipeline: prep -> gemm1 -> gemm2(+stats) -> stats_combine -> gemm3.
//
// Workspace (96 MiB, lifetime-aliased):
//   [0,16M):   n2t  f16 (prep -> gemm2)
//   [16,32M):  Xt   f16 (gemm1 -> gemm2)
//   [32,34M):  Wf   f16 (prep -> gemm1; overlaid by Et)
//   [32,64M):  Et   f16 (gemm2 -> gemm3)
//   [64M+):    Pm/Ps partials, Sc stats

typedef _Float16 f16;
typedef _Float16 f16x8 __attribute__((ext_vector_type(8)));
typedef _Float16 f16x4 __attribute__((ext_vector_type(4)));
typedef float f32x4 __attribute__((ext_vector_type(4)));

#define L2E 1.442695040888963f

// Barrier with LDS-drain only (no vmcnt drain): prefetch survives it.
#define WG_BARRIER() asm volatile("s_waitcnt lgkmcnt(0)\ns_barrier" ::: "memory")

// f32 pair -> f16x8 (RTN, same as prep's old cast)
__device__ __forceinline__ f16x8 cvt8(f32x4 lo, f32x4 hi) {
    f16x8 o;
#pragma unroll
    for (int i = 0; i < 4; ++i) { o[i] = (f16)lo[i]; o[4 + i] = (f16)hi[i]; }
    return o;
}

// exp-scale of a staged B vector: At = exp2(Et*log2e - Sc)
__device__ __forceinline__ f16x8 expb(f16x8 b, f32x4 cl, f32x4 ch) {
    f16x8 t;
#pragma unroll
    for (int i = 0; i < 4; ++i) t[i] = (f16)exp2f(fmaf((float)b[i], L2E, -cl[i]));
#pragma unroll
    for (int i = 0; i < 4; ++i) t[4 + i] = (f16)exp2f(fmaf((float)b[4 + i], L2E, -ch[i]));
    return t;
}

// ---------------------------------------------------------------------------
// Pre-pass: [0,512): Wc -> Wf ; [512,2560): n2 -> n2t (transposed f16).
__global__ __launch_bounds__(256) void prep(const float* __restrict__ Wc,
                                            const float* __restrict__ n2,
                                            f16* __restrict__ Wf,
                                            f16* __restrict__ n2t) {
    const int bid = blockIdx.x, tid = threadIdx.x;
    if (bid < 512) {
        const size_t i = ((size_t)bid * 256 + tid) * 8;
        f32x4 a = *(const f32x4*)(Wc + i);
        f32x4 b = *(const f32x4*)(Wc + i + 4);
        *(f16x8*)(Wf + i) = cvt8(a, b);
        return;
    }
    const int id = bid - 512;
    const int b = id >> 7;
    const int ry = (id & 127) >> 4;
    const int cx = id & 15;
    const float* S = n2 + (size_t)b * 512 * 1024;
    f16* Dt = n2t + (size_t)b * 1024 * 512;
    __shared__ f16 Ts[64 * 72];
    const int r0 = ry * 64, c0 = cx * 64;
    const int rr = tid >> 3, cc8 = (tid & 7) * 8;
#pragma unroll
    for (int h = 0; h < 2; ++h) {
        const int row = r0 + rr + 32 * h;
        const float* s = S + (size_t)row * 1024 + c0 + cc8;
        f32x4 a = *(const f32x4*)s, bq = *(const f32x4*)(s + 4);
        *(f16x8*)&Ts[(rr + 32 * h) * 72 + cc8] = cvt8(a, bq);
    }
    __syncthreads();
    const int j = tid >> 2, k16 = (tid & 3) * 16;
    f16* d = Dt + (size_t)(c0 + j) * 512 + r0 + k16;
    f16x8 o0, o1;
#pragma unroll
    for (int i = 0; i < 8; ++i) {
        o0[i] = Ts[(k16 + i) * 72 + j];
        o1[i] = Ts[(k16 + 8 + i) * 72 + j];
    }
    *(f16x8*)d = o0;
    *(f16x8*)(d + 8) = o1;
}

// ---------------------------------------------------------------------------
// stats_combine: per (b,o) fold 8 partials (log2 domain) ->
//   Sc[b][o] = log2(sum_h e^{E[o][h]}), log2 units.
// Partial layout: Pm[((b*4 + mt)*8 + nt)*256 + ml], mt = o>>8, ml = o&255.
__global__ __launch_bounds__(256) void stats_combine(const float* __restrict__ Pm,
                                                     const float* __restrict__ Ps,
                                                     float* __restrict__ Sc) {
    const int g = blockIdx.x * 256 + threadIdx.x;  // 16 * 1024
    const int b = g >> 10, o = g & 1023;
    const int mt = o >> 8, ml = o & 255;
    const float* pm = Pm + ((size_t)(b * 4 + mt) * 8) * 256 + ml;
    const float* ps = Ps + ((size_t)(b * 4 + mt) * 8) * 256 + ml;
    float M = -3.0e38f;
#pragma unroll
    for (int p = 0; p < 8; ++p) M = fmaxf(M, pm[p * 256]);
    float S = 0.f;
#pragma unroll
    for (int p = 0; p < 8; ++p) S += ps[p * 256] * exp2f(pm[p * 256] - M);
    Sc[g] = M + __log2f(S);
}

// ---------------------------------------------------------------------------
// Shared K-loop core, f16 A (gemm2). BM=256, BN=128, BK=32, 512 threads,
// 8 waves (4m x 2n), wave tile 64x64: 16 MFMA per 8 ds_read_b128.
// LDS: A0 @0 (16K), A1 @16384, B0 @32768 (8K), B1 @40960. Row = 64 B.
// Swizzle: 16B slot s of row r lives at s ^ ((r>>1)&3) (write side sOff,
// read side swz16). Depth-2 global->reg prefetch.
template <int NS>
__device__ __forceinline__ void gemm_core(const char* gA0, const char* gA1,
                                          const char* gB, char* SM, int sOff,
                                          int wm, int wn, int col, int swz16,
                                          f32x4 (&acc)[4][4]) {
    f16x8 a00 = *(const f16x8*)gA0, a01 = *(const f16x8*)gA1;
    f16x8 b0 = *(const f16x8*)gB;
    {
        char* dA = SM + sOff;
        *(f16x8*)dA = a00;
        *(f16x8*)(dA + 8192) = a01;
        *(f16x8*)(SM + 32768 + sOff) = b0;
    }
    f16x8 a10 = *(const f16x8*)(gA0 + 64), a11 = *(const f16x8*)(gA1 + 64);
    f16x8 b1 = *(const f16x8*)(gB + 64);
    a00 = *(const f16x8*)(gA0 + 128); a01 = *(const f16x8*)(gA1 + 128);
    b0 = *(const f16x8*)(gB + 128);
    WG_BARRIER();
#pragma unroll
    for (int kb = 0; kb < NS; ++kb) {
        const char* Ac = SM + (kb & 1) * 16384;
        const char* Bc = SM + 32768 + (kb & 1) * 8192;
        f16x8 fa[4], fb[4];
#pragma unroll
        for (int u = 0; u < 4; ++u)
            fa[u] = *(const f16x8*)(Ac + (wm + u * 16 + col) * 64 + swz16);
#pragma unroll
        for (int v = 0; v < 4; ++v)
            fb[v] = *(const f16x8*)(Bc + (wn + v * 16 + col) * 64 + swz16);
#pragma unroll
        for (int u = 0; u < 4; ++u)
#pragma unroll
            for (int v = 0; v < 4; ++v)
                acc[u][v] = __builtin_amdgcn_mfma_f32_16x16x32_f16(fa[u], fb[v],
                                                                   acc[u][v], 0, 0, 0);
        if (kb + 1 < NS) {
            char* dA = SM + ((kb + 1) & 1) * 16384 + sOff;
            char* dB = SM + 32768 + ((kb + 1) & 1) * 8192 + sOff;
            if ((kb & 1) == 0) {
                *(f16x8*)dA = a10;
                *(f16x8*)(dA + 8192) = a11;
                *(f16x8*)dB = b1;
                if (kb + 3 < NS) {
                    a10 = *(const f16x8*)(gA0 + (size_t)(kb + 3) * 64);
                    a11 = *(const f16x8*)(gA1 + (size_t)(kb + 3) * 64);
                    b1 = *(const f16x8*)(gB + (size_t)(kb + 3) * 64);
                }
            } else {
                *(f16x8*)dA = a00;
                *(f16x8*)(dA + 8192) = a01;
                *(f16x8*)dB = b0;
                if (kb + 3 < NS) {
                    a00 = *(const f16x8*)(gA0 + (size_t)(kb + 3) * 64);
                    a01 = *(const f16x8*)(gA1 + (size_t)(kb + 3) * 64);
                    b0 = *(const f16x8*)(gB + (size_t)(kb + 3) * 64);
                }
            }
            WG_BARRIER();
        }
    }
}

// ---------------------------------------------------------------------------
// K-loop core with f32 A (gemm1/gemm3): A loaded as f32x4 pairs, converted
// to f16 at ds_write time (RTN; numerically identical to the old prep).
// A step stride = 128 B (32 f32). Optional EXPB for gemm3's B-staging.
template <int NS, bool EXPB>
__device__ __forceinline__ void gemm_core_a32(const char* gA0, const char* gA1,
                                              const char* gB, const float* gSp,
                                              char* SM, int sOff, int wm, int wn,
                                              int col, int swz16, f32x4 (&acc)[4][4]) {
    f32x4 c00, c01, c10, c11;
    f32x4 a00l = *(const f32x4*)gA0, a00h = *(const f32x4*)(gA0 + 16);
    f32x4 a01l = *(const f32x4*)gA1, a01h = *(const f32x4*)(gA1 + 16);
    f16x8 b0 = *(const f16x8*)gB;
    if (EXPB) { c00 = *(const f32x4*)gSp; c01 = *(const f32x4*)(gSp + 4); }
    {
        char* dA = SM + sOff;
        *(f16x8*)dA = cvt8(a00l, a00h);
        *(f16x8*)(dA + 8192) = cvt8(a01l, a01h);
        char* dB = SM + 32768 + sOff;
        *(f16x8*)dB = EXPB ? expb(b0, c00, c01) : b0;
    }
    f32x4 a10l = *(const f32x4*)(gA0 + 128), a10h = *(const f32x4*)(gA0 + 144);
    f32x4 a11l = *(const f32x4*)(gA1 + 128), a11h = *(const f32x4*)(gA1 + 144);
    f16x8 b1 = *(const f16x8*)(gB + 64);
    if (EXPB) { c10 = *(const f32x4*)(gSp + 32); c11 = *(const f32x4*)(gSp + 36); }
    a00l = *(const f32x4*)(gA0 + 256); a00h = *(const f32x4*)(gA0 + 272);
    a01l = *(const f32x4*)(gA1 + 256); a01h = *(const f32x4*)(gA1 + 272);
    b0 = *(const f16x8*)(gB + 128);
    if (EXPB) { c00 = *(const f32x4*)(gSp + 64); c01 = *(const f32x4*)(gSp + 68); }
    WG_BARRIER();
#pragma unroll
    for (int kb = 0; kb < NS; ++kb) {
        const char* Ac = SM + (kb & 1) * 16384;
        const char* Bc = SM + 32768 + (kb & 1) * 8192;
        f16x8 fa[4], fb[4];
#pragma unroll
        for (int u = 0; u < 4; ++u)
            fa[u] = *(const f16x8*)(Ac + (wm + u * 16 + col) * 64 + swz16);
#pragma unroll
        for (int v = 0; v < 4; ++v)
            fb[v] = *(const f16x8*)(Bc + (wn + v * 16 + col) * 64 + swz16);
#pragma unroll
        for (int u = 0; u < 4; ++u)
#pragma unroll
            for (int v = 0; v < 4; ++v)
                acc[u][v] = __builtin_amdgcn_mfma_f32_16x16x32_f16(fa[u], fb[v],
                                                                   acc[u][v], 0, 0, 0);
        if (kb + 1 < NS) {
            char* dA = SM + ((kb + 1) & 1) * 16384 + sOff;
            char* dB = SM + 32768 + ((kb + 1) & 1) * 8192 + sOff;
            if ((kb & 1) == 0) {
                *(f16x8*)dA = cvt8(a10l, a10h);
                *(f16x8*)(dA + 8192) = cvt8(a11l, a11h);
                *(f16x8*)dB = EXPB ? expb(b1, c10, c11) : b1;
                if (kb + 3 < NS) {
                    a10l = *(const f32x4*)(gA0 + (size_t)(kb + 3) * 128);
                    a10h = *(const f32x4*)(gA0 + (size_t)(kb + 3) * 128 + 16);
                    a11l = *(const f32x4*)(gA1 + (size_t)(kb + 3) * 128);
                    a11h = *(const f32x4*)(gA1 + (size_t)(kb + 3) * 128 + 16);
                    b1 = *(const f16x8*)(gB + (size_t)(kb + 3) * 64);
                    if (EXPB) {
                        c10 = *(const f32x4*)(gSp + (size_t)(kb + 3) * 32);
                        c11 = *(const f32x4*)(gSp + (size_t)(kb + 3) * 32 + 4);
                    }
                }
            } else {
                *(f16x8*)dA = cvt8(a00l, a00h);
                *(f16x8*)(dA + 8192) = cvt8(a01l, a01h);
                *(f16x8*)dB = EXPB ? expb(b0, c00, c01) : b0;
                if (kb + 3 < NS) {
                    a00l = *(const f32x4*)(gA0 + (size_t)(kb + 3) * 128);
                    a00h = *(const f32x4*)(gA0 + (size_t)(kb + 3) * 128 + 16);
                    a01l = *(const f32x4*)(gA1 + (size_t)(kb + 3) * 128);
                    a01h = *(const f32x4*)(gA1 + (size_t)(kb + 3) * 128 + 16);
                    b0 = *(const f16x8*)(gB + (size_t)(kb + 3) * 64);
                    if (EXPB) {
                        c00 = *(const f32x4*)(gSp + (size_t)(kb + 3) * 32);
                        c01 = *(const f32x4*)(gSp + (size_t)(kb + 3) * 32 + 4);
                    }
                }
            }
            WG_BARRIER();
        }
    }
}

// Transposed f16 epilogue: two m-half passes through Tt[128][136].
__device__ __forceinline__ void epilogue_tr(f32x4 (&acc)[4][4], char* SM, f16* dst0,
                                            int dstRow, int m0, int n0, int tid) {
    const int lane = tid & 63, wave = tid >> 6;
    const int col = lane & 15, quad = lane >> 4;
    const int wn = (wave >> 2) * 64;
    const int mh_w = (wave >> 1) & 1;
    const int wm_loc = (wave & 1) * 64;
    const int j = tid >> 2, seg = (tid & 3) * 32;
    WG_BARRIER();  // all frag reads of SM done before overwrite
    f16* Tt = (f16*)SM;
#pragma unroll
    for (int mh = 0; mh < 2; ++mh) {
        if (mh_w == mh) {
#pragma unroll
            for (int u = 0; u < 4; ++u)
#pragma unroll
                for (int v = 0; v < 4; ++v) {
                    f16x4 p;
#pragma unroll
                    for (int r = 0; r < 4; ++r) p[r] = (f16)acc[u][v][r];
                    *(f16x4*)&Tt[(wn + v * 16 + col) * 136 + wm_loc + u * 16 + quad * 4] = p;
                }
        }
        WG_BARRIER();
        f16* dst = dst0 + (size_t)(n0 + j) * dstRow + m0 + mh * 128 + seg;
#pragma unroll
        for (int c8 = 0; c8 < 32; c8 += 8)
            *(f16x8*)(dst + c8) = *(const f16x8*)&Tt[j * 136 + seg + c8];
        if (mh == 0) WG_BARRIER();
    }
}

// ---------------------------------------------------------------------------
// GEMM1: Xt[b][o][c] = (n1[b] @ Wf^T)^T.  A = n1 f32 (converted at staging).
// M=512, N=1024, K=1024. 256 blocks.
__global__ __launch_bounds__(512) void gemm1_nt_xt(const float* __restrict__ A,
                                                   const f16* __restrict__ Bw,
                                                   f16* __restrict__ Xt) {
    const int K = 1024;
    const int id = blockIdx.x;
    const int xcd = id & 7, loc = id >> 3;         // loc 0..31
    const int b = xcd * 2 + (loc >> 4);
    const int m0 = ((loc >> 3) & 1) * 256;
    const int n0 = (loc & 7) * 128;
    A += (size_t)b * 512 * K;
    Xt += (size_t)b * 1024 * 512;
    __shared__ __attribute__((aligned(16))) char SM[49152];
    const int tid = threadIdx.x, lane = tid & 63, wave = tid >> 6;
    const int col = lane & 15, quad = lane >> 4;
    const int wm = (wave & 3) * 64, wn = (wave >> 2) * 64;
    const int srow = tid >> 2, sslot = tid & 3;
    const int sOff = srow * 64 + ((sslot ^ ((srow >> 1) & 3)) * 16);
    const int swz16 = (quad ^ ((col >> 1) & 3)) * 16;
    const char* gA0 = (const char*)A + (size_t)(m0 + srow) * K * 4 + sslot * 32;
    const char* gA1 = gA0 + (size_t)128 * K * 4;
    const char* gB = (const char*)Bw + (size_t)(n0 + srow) * K * 2 + sslot * 16;
    f32x4 acc[4][4] = {};
    gemm_core_a32<32, false>(gA0, gA1, gB, nullptr, SM, sOff, wm, wn, col, swz16, acc);
    epilogue_tr(acc, SM, Xt, 512, m0, n0, tid);
}

// ---------------------------------------------------------------------------
// GEMM2: Et[b][h][o] (f16) = (Xt[b] @ n2t[b]^T)^T.  M=1024, N=1024, K=512.
// 512 blocks. Epilogue fuses column-softmax partials computed FROM Tt (the
// f16-rounded tile in LDS, bit-consistent with stored Et). Register-lean.
__global__ __launch_bounds__(512) void gemm2_nt_et(const f16* __restrict__ A,
                                                   const f16* __restrict__ B,
                                                   f16* __restrict__ Et,
                                                   float* __restrict__ Pm,
                                                   float* __restrict__ Ps) {
    const int K = 512;
    const int id = blockIdx.x;
    const int xcd = id & 7, loc = id >> 3;         // loc 0..63
    const int b = xcd * 2 + (loc >> 5);
    const int m0 = ((loc >> 3) & 3) * 256;
    const int n0 = (loc & 7) * 128;
    A += (size_t)b * 1024 * K;
    B += (size_t)b * 1024 * K;
    Et += (size_t)b * 1024 * 1024;
    __shared__ __attribute__((aligned(16))) char SM[49152];
    const int tid = threadIdx.x, lane = tid & 63, wave = tid >> 6;
    const int col = lane & 15, quad = lane >> 4;
    const int wm = (wave & 3) * 64, wn = (wave >> 2) * 64;
    const int srow = tid >> 2, sslot = tid & 3;
    const int sOff = srow * 64 + ((sslot ^ ((srow >> 1) & 3)) * 16);
    const int swz16 = (quad ^ ((col >> 1) & 3)) * 16;
    const char* gA0 = (const char*)A + (size_t)(m0 + srow) * K * 2 + sslot * 16;
    const char* gA1 = gA0 + (size_t)128 * K * 2;
    const char* gB = (const char*)B + (size_t)(n0 + srow) * K * 2 + sslot * 16;
    f32x4 acc[4][4] = {};
    gemm_core<16>(gA0, gA1, gB, SM, sOff, wm, wn, col, swz16, acc);

    // ---- transposed epilogue + fused column-softmax stats from Tt.
    {
        const int wn_e = (wave >> 2) * 64;
        const int mh_w = (wave >> 1) & 1;
        const int wm_loc = (wave & 1) * 64;
        const int j = tid >> 2, seg = (tid & 3) * 32;
        const int scol = tid >> 2, srq = tid & 3;   // o-column, row-quarter
        WG_BARRIER();  // all frag reads of SM done before overwrite
        f16* Tt = (f16*)SM;
#pragma unroll
        for (int mh = 0; mh < 2; ++mh) {
            if (mh_w == mh) {
#pragma unroll
                for (int u = 0; u < 4; ++u)
#pragma unroll
                    for (int v = 0; v < 4; ++v) {
                        f16x4 p;
#pragma unroll
                        for (int r = 0; r < 4; ++r) p[r] = (f16)acc[u][v][r];
                        *(f16x4*)&Tt[(wn_e + v * 16 + col) * 136 + wm_loc + u * 16 + quad * 4] = p;
                    }
            }
            WG_BARRIER();
            // coalesced Et rows
            f16* dst = Et + (size_t)(n0 + j) * 1024 + m0 + mh * 128 + seg;
#pragma unroll
            for (int c8 = 0; c8 < 32; c8 += 8)
                *(f16x8*)(dst + c8) = *(const f16x8*)&Tt[j * 136 + seg + c8];
            // stats: o = m0 + mh*128 + scol; rows srq*32..+32 (rotated reads).
            float mx = -3.0e38f;
#pragma unroll
            for (int n = 0; n < 32; ++n) {
                const int row = srq * 32 + ((n + scol) & 31);
                mx = fmaxf(mx, (float)Tt[row * 136 + scol]);
            }
            const float mxl = mx * L2E;
            float s = 0.f;
#pragma unroll
            for (int n = 0; n < 32; ++n) {
                const int row = srq * 32 + ((n + scol) & 31);
                s += exp2f(fmaf((float)Tt[row * 136 + scol], L2E, -mxl));
            }
            float pmv = mxl, psv = s;
#pragma unroll
            for (int d = 1; d < 4; d <<= 1) {
                float om = __shfl_xor(pmv, d, 64);
                float os = __shfl_xor(psv, d, 64);
                float nm = fmaxf(pmv, om);
                psv = psv * exp2f(pmv - nm) + os * exp2f(om - nm);
                pmv = nm;
            }
            if (srq == 0) {
                const int part = (b * 4 + (m0 >> 8)) * 8 + (n0 >> 7);
                const int ml = mh * 128 + scol;
                Pm[(size_t)part * 256 + ml] = pmv;
                Ps[(size_t)part * 256 + ml] = psv;
            }
            if (mh == 0) WG_BARRIER();
        }
    }
}

// ---------------------------------------------------------------------------
// GEMM3: out[b][c][j] (f32) = n2[b](f32->f16 at staging) @ At[b]^T, with
// At[j][o] = exp2(Et[j][o]*log2e - Sc[b][o]) applied at B-staging.
// M=512, N=1024, K=1024. 256 blocks.
__global__ __launch_bounds__(512) void gemm3_nt_out(const float* __restrict__ A,
                                                    const f16* __restrict__ Et,
                                                    const float* __restrict__ Sc,
                                                    float* __restrict__ C) {
    const int K = 1024;
    const int id = blockIdx.x;
    const int xcd = id & 7, loc = id >> 3;         // loc 0..31
    const int b = xcd * 2 + (loc >> 4);
    const int m0 = ((loc >> 3) & 1) * 256;
    const int n0 = (loc & 7) * 128;
    A += (size_t)b * 512 * K;
    Et += (size_t)b * 1024 * K;
    Sc += (size_t)b * 1024;
    C += (size_t)b * 512 * 1024;
    __shared__ __attribute__((aligned(16))) char SM[49152];
    const int tid = threadIdx.x, lane = tid & 63, wave = tid >> 6;
    const int col = lane & 15, quad = lane >> 4;
    const int wm = (wave & 3) * 64, wn = (wave >> 2) * 64;
    const int srow = tid >> 2, sslot = tid & 3;
    const int sOff = srow * 64 + ((sslot ^ ((srow >> 1) & 3)) * 16);
    const int swz16 = (quad ^ ((col >> 1) & 3)) * 16;
    const char* gA0 = (const char*)A + (size_t)(m0 + srow) * K * 4 + sslot * 32;
    const char* gA1 = gA0 + (size_t)128 * K * 4;
    const char* gB = (const char*)Et + (size_t)(n0 + srow) * K * 2 + sslot * 16;
    const float* gSp = Sc + sslot * 8;  // o-base of this thread's 8 staged elems
    f32x4 acc[4][4] = {};
    gemm_core_a32<32, true>(gA0, gA1, gB, gSp, SM, sOff, wm, wn, col, swz16, acc);

#pragma unroll
    for (int u = 0; u < 4; ++u)
#pragma unroll
        for (int v = 0; v < 4; ++v)
#pragma unroll
            for (int r = 0; r < 4; ++r)
                C[(size_t)(m0 + wm + u * 16 + quad * 4 + r) * 1024 + n0 + wn + v * 16 + col] =
                    acc[u][v][r];
}

// ---------------------------------------------------------------------------
extern "C" void kernel_launch(void* const* d_in, const int* in_sizes, int n_in,
                              void* d_out, int out_size, void* d_ws, size_t ws_size,
                              hipStream_t stream) {
    const float* n1 = (const float*)d_in[0];
    const float* n2 = (const float*)d_in[1];
    const float* Wc = (const float*)d_in[2];
    float* out = (float*)d_out;
    char* ws = (char*)d_ws;

    f16* n2t = (f16*)(ws);                   // [0,16M)   prep -> gemm2
    f16* Xt  = (f16*)(ws + (16u << 20));     // [16,32M)  gemm1 -> gemm2
    f16* Wf  = (f16*)(ws + (32u << 20));     // [32,34M)  prep -> gemm1 (dead before Et)
    f16* Et  = (f16*)(ws + (32u << 20));     // [32,64M)  gemm2 -> gemm3
    float* Pm = (float*)(ws + (64u << 20));  // 512 KiB
    float* Ps = (float*)(ws + (65u << 20));  // 512 KiB
    float* Sc = (float*)(ws + (66u << 20));  // 64 KiB (log2 units)

    prep<<<2560, dim3(256), 0, stream>>>(Wc, n2, Wf, n2t);
    gemm1_nt_xt<<<256, dim3(512), 0, stream>>>(n1, Wf, Xt);
    gemm2_nt_et<<<512, dim3(512), 0, stream>>>(Xt, n2t, Et, Pm, Ps);
    stats_combine<<<64, dim3(256), 0, stream>>>(Pm, Ps, Sc);
    gemm3_nt_out<<<256, dim3(512), 0, stream>>>(n2, Et, Sc, out);
}

// Round 11
// 200.439 us; speedup vs baseline: 1.0182x; 1.0182x over previous
//
#include <hip/hip_runtime.h>
#include <math.h>

// B=16, C=512, HW=1024.  Chain (per batch):
//   X  (C x HW)  = n1 @ W_c^T
//   E  (HW x HW) = X^T @ n2
//   A  = row-softmax(E)
//   out(C x HW)  = n2 @ A
//
// Round 18: counted-vmcnt DMA core (T3/T4 minimum form) for gemm1+gemm2.
//  - K-loop: raw s_barrier + s_waitcnt vmcnt(3) -- the wait at step kb is
//    for data DMA'd TWO steps earlier; step kb+1's 3 loads stay in flight
//    across barriers (never drain to 0 in the main loop; R7's failure was
//    the __syncthreads vmcnt(0) drain every step).
//  - Staging via global_load_lds(16B): wave-uniform LDS dest (linear),
//    pre-swizzled global source (slot ls^((r>>1)&3)) so fragment reads keep
//    the verified swz16 pattern. This swizzle discipline passed in R7.
//  - gemm3 unchanged (R10 reg-staged a32 core + exp fused at B-staging;
//    DMA cannot format-convert). gemm1's A back to f16 via restored n1f.
//  - gemm2 keeps the lean Tt-based stats fusion (R9-verified numerics).
//  - Pipeline: prep -> gemm1 -> gemm2(+stats) -> stats_combine -> gemm3.
//
// Workspace (96 MiB, lifetime-aliased):
//   [0,16M):   n2t  f16 (prep -> gemm2)
//   [16,32M):  Xt   f16 (gemm1 -> gemm2)
//   [32,34M):  Wf   f16 (prep -> gemm1; overlaid by Et)
//   [32,64M):  Et   f16 (gemm2 -> gemm3)
//   [64,80M):  n1f  f16 (prep -> gemm1)
//   [80M+):    Pm/Ps partials, Sc stats

typedef _Float16 f16;
typedef _Float16 f16x8 __attribute__((ext_vector_type(8)));
typedef _Float16 f16x4 __attribute__((ext_vector_type(4)));
typedef float f32x4 __attribute__((ext_vector_type(4)));

#define L2E 1.442695040888963f

// Barrier with LDS-drain only (no vmcnt drain): prefetch survives it.
#define WG_BARRIER() asm volatile("s_waitcnt lgkmcnt(0)\ns_barrier" ::: "memory")

#define DMA16(g, l)                                                             \
    __builtin_amdgcn_global_load_lds(                                           \
        (const __attribute__((address_space(1))) void*)(g),                     \
        (__attribute__((address_space(3))) void*)(l), 16, 0, 0)

// f32 pair -> f16x8 (RTN)
__device__ __forceinline__ f16x8 cvt8(f32x4 lo, f32x4 hi) {
    f16x8 o;
#pragma unroll
    for (int i = 0; i < 4; ++i) { o[i] = (f16)lo[i]; o[4 + i] = (f16)hi[i]; }
    return o;
}

// exp-scale of a staged B vector: At = exp2(Et*log2e - Sc)
__device__ __forceinline__ f16x8 expb(f16x8 b, f32x4 cl, f32x4 ch) {
    f16x8 t;
#pragma unroll
    for (int i = 0; i < 4; ++i) t[i] = (f16)exp2f(fmaf((float)b[i], L2E, -cl[i]));
#pragma unroll
    for (int i = 0; i < 4; ++i) t[4 + i] = (f16)exp2f(fmaf((float)b[4 + i], L2E, -ch[i]));
    return t;
}

// ---------------------------------------------------------------------------
// Pre-pass. blockIdx.x:
//   [0,4096):    n1 -> n1f     [4096,4608): Wc -> Wf
//   [4608,6656): n2 -> n2t (transposed f16; no n2f -- gemm3 reads n2 f32)
__global__ __launch_bounds__(256) void prep(const float* __restrict__ n1,
                                            const float* __restrict__ Wc,
                                            const float* __restrict__ n2,
                                            f16* __restrict__ n1f, f16* __restrict__ Wf,
                                            f16* __restrict__ n2t) {
    const int bid = blockIdx.x, tid = threadIdx.x;
    if (bid < 4608) {
        const float* s = (bid < 4096) ? n1 : Wc;
        f16* d = (bid < 4096) ? n1f : Wf;
        const size_t i = ((size_t)(bid < 4096 ? bid : bid - 4096) * 256 + tid) * 8;
        f32x4 a = *(const f32x4*)(s + i);
        f32x4 b = *(const f32x4*)(s + i + 4);
        *(f16x8*)(d + i) = cvt8(a, b);
        return;
    }
    const int id = bid - 4608;
    const int b = id >> 7;
    const int ry = (id & 127) >> 4;
    const int cx = id & 15;
    const float* S = n2 + (size_t)b * 512 * 1024;
    f16* Dt = n2t + (size_t)b * 1024 * 512;
    __shared__ f16 Ts[64 * 72];
    const int r0 = ry * 64, c0 = cx * 64;
    const int rr = tid >> 3, cc8 = (tid & 7) * 8;
#pragma unroll
    for (int h = 0; h < 2; ++h) {
        const int row = r0 + rr + 32 * h;
        const float* s = S + (size_t)row * 1024 + c0 + cc8;
        f32x4 a = *(const f32x4*)s, bq = *(const f32x4*)(s + 4);
        *(f16x8*)&Ts[(rr + 32 * h) * 72 + cc8] = cvt8(a, bq);
    }
    __syncthreads();
    const int j = tid >> 2, k16 = (tid & 3) * 16;
    f16* d = Dt + (size_t)(c0 + j) * 512 + r0 + k16;
    f16x8 o0, o1;
#pragma unroll
    for (int i = 0; i < 8; ++i) {
        o0[i] = Ts[(k16 + i) * 72 + j];
        o1[i] = Ts[(k16 + 8 + i) * 72 + j];
    }
    *(f16x8*)d = o0;
    *(f16x8*)(d + 8) = o1;
}

// ---------------------------------------------------------------------------
// stats_combine: per (b,o) fold 8 partials (log2 domain) ->
//   Sc[b][o] = log2(sum_h e^{E[o][h]}), log2 units.
__global__ __launch_bounds__(256) void stats_combine(const float* __restrict__ Pm,
                                                     const float* __restrict__ Ps,
                                                     float* __restrict__ Sc) {
    const int g = blockIdx.x * 256 + threadIdx.x;  // 16 * 1024
    const int b = g >> 10, o = g & 1023;
    const int mt = o >> 8, ml = o & 255;
    const float* pm = Pm + ((size_t)(b * 4 + mt) * 8) * 256 + ml;
    const float* ps = Ps + ((size_t)(b * 4 + mt) * 8) * 256 + ml;
    float M = -3.0e38f;
#pragma unroll
    for (int p = 0; p < 8; ++p) M = fmaxf(M, pm[p * 256]);
    float S = 0.f;
#pragma unroll
    for (int p = 0; p < 8; ++p) S += ps[p * 256] * exp2f(pm[p * 256] - M);
    Sc[g] = M + __log2f(S);
}

// ---------------------------------------------------------------------------
// Counted-vmcnt DMA K-loop core. BM=256, BN=128, BK=32, 512 threads, 8 waves
// (4m x 2n), wave tile 64x64: 16 MFMA per 8 ds_read_b128 per step.
// LDS: A bufs @0/16384 (16K each), B bufs @32768/40960 (8K each).
// Per wave per step: 3 DMA16 (A rows lo, A rows hi, B), wave-uniform dest.
// Global source pre-swizzled (slot ls ^ ((r>>1)&3)); reads use swz16.
// Schedule per step kb:  vmcnt(3); s_barrier;  ds_read frags;  lgkmcnt(0);
// s_barrier;  DMA step kb+2 into buf just read;  MFMA.  Loads for step kb+1
// stay in flight across both barriers (never drained mid-loop).
template <int NS>
__device__ __forceinline__ void gemm_dmac(const char* sA0, const char* sA1,
                                          const char* sB, char* dA, char* dB,
                                          char* SM, int wm, int wn, int col,
                                          int swz16, f32x4 (&acc)[4][4]) {
    // prologue: step0 -> buf0, step1 -> buf1
    DMA16(sA0, dA); DMA16(sA1, dA + 8192); DMA16(sB, dB);
    DMA16(sA0 + 64, dA + 16384); DMA16(sA1 + 64, dA + 24576); DMA16(sB + 64, dB + 8192);
#pragma unroll
    for (int kb = 0; kb < NS; ++kb) {
        if (kb + 1 < NS) asm volatile("s_waitcnt vmcnt(3)" ::: "memory");
        else             asm volatile("s_waitcnt vmcnt(0)" ::: "memory");
        __builtin_amdgcn_s_barrier();
        asm volatile("" ::: "memory");
        const char* Ac = SM + (kb & 1) * 16384;
        const char* Bc = SM + 32768 + (kb & 1) * 8192;
        f16x8 fa[4], fb[4];
#pragma unroll
        for (int u = 0; u < 4; ++u)
            fa[u] = *(const f16x8*)(Ac + (wm + u * 16 + col) * 64 + swz16);
#pragma unroll
        for (int v = 0; v < 4; ++v)
            fb[v] = *(const f16x8*)(Bc + (wn + v * 16 + col) * 64 + swz16);
        asm volatile("s_waitcnt lgkmcnt(0)" ::: "memory");
        __builtin_amdgcn_s_barrier();
        asm volatile("" ::: "memory");
        if (kb + 2 < NS) {
            const int o = (kb + 2) * 64;
            char* da = dA + (kb & 1) * 16384;
            char* db = dB + (kb & 1) * 8192;
            DMA16(sA0 + o, da); DMA16(sA1 + o, da + 8192); DMA16(sB + o, db);
        }
#pragma unroll
        for (int u = 0; u < 4; ++u)
#pragma unroll
            for (int v = 0; v < 4; ++v)
                acc[u][v] = __builtin_amdgcn_mfma_f32_16x16x32_f16(fa[u], fb[v],
                                                                   acc[u][v], 0, 0, 0);
    }
}

// ---------------------------------------------------------------------------
// Reg-staged core with f32 A + EXPB (gemm3, unchanged from R10).
template <int NS, bool EXPB>
__device__ __forceinline__ void gemm_core_a32(const char* gA0, const char* gA1,
                                              const char* gB, const float* gSp,
                                              char* SM, int sOff, int wm, int wn,
                                              int col, int swz16, f32x4 (&acc)[4][4]) {
    f32x4 c00, c01, c10, c11;
    f32x4 a00l = *(const f32x4*)gA0, a00h = *(const f32x4*)(gA0 + 16);
    f32x4 a01l = *(const f32x4*)gA1, a01h = *(const f32x4*)(gA1 + 16);
    f16x8 b0 = *(const f16x8*)gB;
    if (EXPB) { c00 = *(const f32x4*)gSp; c01 = *(const f32x4*)(gSp + 4); }
    {
        char* dA = SM + sOff;
        *(f16x8*)dA = cvt8(a00l, a00h);
        *(f16x8*)(dA + 8192) = cvt8(a01l, a01h);
        char* dB = SM + 32768 + sOff;
        *(f16x8*)dB = EXPB ? expb(b0, c00, c01) : b0;
    }
    f32x4 a10l = *(const f32x4*)(gA0 + 128), a10h = *(const f32x4*)(gA0 + 144);
    f32x4 a11l = *(const f32x4*)(gA1 + 128), a11h = *(const f32x4*)(gA1 + 144);
    f16x8 b1 = *(const f16x8*)(gB + 64);
    if (EXPB) { c10 = *(const f32x4*)(gSp + 32); c11 = *(const f32x4*)(gSp + 36); }
    a00l = *(const f32x4*)(gA0 + 256); a00h = *(const f32x4*)(gA0 + 272);
    a01l = *(const f32x4*)(gA1 + 256); a01h = *(const f32x4*)(gA1 + 272);
    b0 = *(const f16x8*)(gB + 128);
    if (EXPB) { c00 = *(const f32x4*)(gSp + 64); c01 = *(const f32x4*)(gSp + 68); }
    WG_BARRIER();
#pragma unroll
    for (int kb = 0; kb < NS; ++kb) {
        const char* Ac = SM + (kb & 1) * 16384;
        const char* Bc = SM + 32768 + (kb & 1) * 8192;
        f16x8 fa[4], fb[4];
#pragma unroll
        for (int u = 0; u < 4; ++u)
            fa[u] = *(const f16x8*)(Ac + (wm + u * 16 + col) * 64 + swz16);
#pragma unroll
        for (int v = 0; v < 4; ++v)
            fb[v] = *(const f16x8*)(Bc + (wn + v * 16 + col) * 64 + swz16);
#pragma unroll
        for (int u = 0; u < 4; ++u)
#pragma unroll
            for (int v = 0; v < 4; ++v)
                acc[u][v] = __builtin_amdgcn_mfma_f32_16x16x32_f16(fa[u], fb[v],
                                                                   acc[u][v], 0, 0, 0);
        if (kb + 1 < NS) {
            char* dA = SM + ((kb + 1) & 1) * 16384 + sOff;
            char* dB = SM + 32768 + ((kb + 1) & 1) * 8192 + sOff;
            if ((kb & 1) == 0) {
                *(f16x8*)dA = cvt8(a10l, a10h);
                *(f16x8*)(dA + 8192) = cvt8(a11l, a11h);
                *(f16x8*)dB = EXPB ? expb(b1, c10, c11) : b1;
                if (kb + 3 < NS) {
                    a10l = *(const f32x4*)(gA0 + (size_t)(kb + 3) * 128);
                    a10h = *(const f32x4*)(gA0 + (size_t)(kb + 3) * 128 + 16);
                    a11l = *(const f32x4*)(gA1 + (size_t)(kb + 3) * 128);
                    a11h = *(const f32x4*)(gA1 + (size_t)(kb + 3) * 128 + 16);
                    b1 = *(const f16x8*)(gB + (size_t)(kb + 3) * 64);
                    if (EXPB) {
                        c10 = *(const f32x4*)(gSp + (size_t)(kb + 3) * 32);
                        c11 = *(const f32x4*)(gSp + (size_t)(kb + 3) * 32 + 4);
                    }
                }
            } else {
                *(f16x8*)dA = cvt8(a00l, a00h);
                *(f16x8*)(dA + 8192) = cvt8(a01l, a01h);
                *(f16x8*)dB = EXPB ? expb(b0, c00, c01) : b0;
                if (kb + 3 < NS) {
                    a00l = *(const f32x4*)(gA0 + (size_t)(kb + 3) * 128);
                    a00h = *(const f32x4*)(gA0 + (size_t)(kb + 3) * 128 + 16);
                    a01l = *(const f32x4*)(gA1 + (size_t)(kb + 3) * 128);
                    a01h = *(const f32x4*)(gA1 + (size_t)(kb + 3) * 128 + 16);
                    b0 = *(const f16x8*)(gB + (size_t)(kb + 3) * 64);
                    if (EXPB) {
                        c00 = *(const f32x4*)(gSp + (size_t)(kb + 3) * 32);
                        c01 = *(const f32x4*)(gSp + (size_t)(kb + 3) * 32 + 4);
                    }
                }
            }
            WG_BARRIER();
        }
    }
}

// Transposed f16 epilogue: two m-half passes through Tt[128][136].
__device__ __forceinline__ void epilogue_tr(f32x4 (&acc)[4][4], char* SM, f16* dst0,
                                            int dstRow, int m0, int n0, int tid) {
    const int lane = tid & 63, wave = tid >> 6;
    const int col = lane & 15, quad = lane >> 4;
    const int wn = (wave >> 2) * 64;
    const int mh_w = (wave >> 1) & 1;
    const int wm_loc = (wave & 1) * 64;
    const int j = tid >> 2, seg = (tid & 3) * 32;
    WG_BARRIER();  // all frag reads of SM done before overwrite
    f16* Tt = (f16*)SM;
#pragma unroll
    for (int mh = 0; mh < 2; ++mh) {
        if (mh_w == mh) {
#pragma unroll
            for (int u = 0; u < 4; ++u)
#pragma unroll
                for (int v = 0; v < 4; ++v) {
                    f16x4 p;
#pragma unroll
                    for (int r = 0; r < 4; ++r) p[r] = (f16)acc[u][v][r];
                    *(f16x4*)&Tt[(wn + v * 16 + col) * 136 + wm_loc + u * 16 + quad * 4] = p;
                }
        }
        WG_BARRIER();
        f16* dst = dst0 + (size_t)(n0 + j) * dstRow + m0 + mh * 128 + seg;
#pragma unroll
        for (int c8 = 0; c8 < 32; c8 += 8)
            *(f16x8*)(dst + c8) = *(const f16x8*)&Tt[j * 136 + seg + c8];
        if (mh == 0) WG_BARRIER();
    }
}

// ---------------------------------------------------------------------------
// GEMM1: Xt[b][o][c] = (n1f[b] @ Wf^T)^T.  M=512, N=1024, K=1024. 256 blocks.
// Counted-vmcnt DMA core.
__global__ __launch_bounds__(512) void gemm1_nt_xt(const f16* __restrict__ A,
                                                   const f16* __restrict__ Bw,
                                                   f16* __restrict__ Xt) {
    const int id = blockIdx.x;
    const int xcd = id & 7, loc = id >> 3;         // loc 0..31
    const int b = xcd * 2 + (loc >> 4);
    const int m0 = ((loc >> 3) & 1) * 256;
    const int n0 = (loc & 7) * 128;
    A += (size_t)b * 512 * 1024;
    Xt += (size_t)b * 1024 * 512;
    __shared__ __attribute__((aligned(16))) char SM[49152];
    const int tid = threadIdx.x, lane = tid & 63, wave = tid >> 6;
    const int col = lane & 15, quad = lane >> 4;
    const int wm = (wave & 3) * 64, wn = (wave >> 2) * 64;
    const int swz16 = (quad ^ ((col >> 1) & 3)) * 16;
    // DMA source/dest (pre-swizzled source, linear wave-uniform dest)
    const int r = wave * 16 + (lane >> 2), ls = lane & 3;
    const int x = (r >> 1) & 3;
    const char* sA0 = (const char*)A + (size_t)(m0 + r) * 2048 + ((ls ^ x) * 16);
    const char* sA1 = sA0 + (size_t)128 * 2048;
    const char* sB  = (const char*)Bw + (size_t)(n0 + r) * 2048 + ((ls ^ x) * 16);
    char* dA = SM + wave * 1024;
    char* dB = SM + 32768 + wave * 1024;
    f32x4 acc[4][4] = {};
    gemm_dmac<32>(sA0, sA1, sB, dA, dB, SM, wm, wn, col, swz16, acc);
    epilogue_tr(acc, SM, Xt, 512, m0, n0, tid);
}

// ---------------------------------------------------------------------------
// GEMM2: Et[b][h][o] (f16) = (Xt[b] @ n2t[b]^T)^T.  M=1024, N=1024, K=512.
// 512 blocks. Counted-vmcnt DMA core + lean Tt-based stats fusion.
__global__ __launch_bounds__(512) void gemm2_nt_et(const f16* __restrict__ A,
                                                   const f16* __restrict__ B,
                                                   f16* __restrict__ Et,
                                                   float* __restrict__ Pm,
                                                   float* __restrict__ Ps) {
    const int id = blockIdx.x;
    const int xcd = id & 7, loc = id >> 3;         // loc 0..63
    const int b = xcd * 2 + (loc >> 5);
    const int m0 = ((loc >> 3) & 3) * 256;
    const int n0 = (loc & 7) * 128;
    A += (size_t)b * 1024 * 512;
    B += (size_t)b * 1024 * 512;
    Et += (size_t)b * 1024 * 1024;
    __shared__ __attribute__((aligned(16))) char SM[49152];
    const int tid = threadIdx.x, lane = tid & 63, wave = tid >> 6;
    const int col = lane & 15, quad = lane >> 4;
    const int wm = (wave & 3) * 64, wn = (wave >> 2) * 64;
    const int swz16 = (quad ^ ((col >> 1) & 3)) * 16;
    const int r = wave * 16 + (lane >> 2), ls = lane & 3;
    const int x = (r >> 1) & 3;
    const char* sA0 = (const char*)A + (size_t)(m0 + r) * 1024 + ((ls ^ x) * 16);
    const char* sA1 = sA0 + (size_t)128 * 1024;
    const char* sB  = (const char*)B + (size_t)(n0 + r) * 1024 + ((ls ^ x) * 16);
    char* dA = SM + wave * 1024;
    char* dB = SM + 32768 + wave * 1024;
    f32x4 acc[4][4] = {};
    gemm_dmac<16>(sA0, sA1, sB, dA, dB, SM, wm, wn, col, swz16, acc);

    // ---- transposed epilogue + fused column-softmax stats from Tt.
    {
        const int wn_e = (wave >> 2) * 64;
        const int mh_w = (wave >> 1) & 1;
        const int wm_loc = (wave & 1) * 64;
        const int j = tid >> 2, seg = (tid & 3) * 32;
        const int scol = tid >> 2, srq = tid & 3;   // o-column, row-quarter
        WG_BARRIER();  // all frag reads of SM done before overwrite
        f16* Tt = (f16*)SM;
#pragma unroll
        for (int mh = 0; mh < 2; ++mh) {
            if (mh_w == mh) {
#pragma unroll
                for (int u = 0; u < 4; ++u)
#pragma unroll
                    for (int v = 0; v < 4; ++v) {
                        f16x4 p;
#pragma unroll
                        for (int r2 = 0; r2 < 4; ++r2) p[r2] = (f16)acc[u][v][r2];
                        *(f16x4*)&Tt[(wn_e + v * 16 + col) * 136 + wm_loc + u * 16 + quad * 4] = p;
                    }
            }
            WG_BARRIER();
            // coalesced Et rows
            f16* dst = Et + (size_t)(n0 + j) * 1024 + m0 + mh * 128 + seg;
#pragma unroll
            for (int c8 = 0; c8 < 32; c8 += 8)
                *(f16x8*)(dst + c8) = *(const f16x8*)&Tt[j * 136 + seg + c8];
            // stats: o = m0 + mh*128 + scol; rows srq*32..+32 (rotated reads).
            float mx = -3.0e38f;
#pragma unroll
            for (int n = 0; n < 32; ++n) {
                const int row = srq * 32 + ((n + scol) & 31);
                mx = fmaxf(mx, (float)Tt[row * 136 + scol]);
            }
            const float mxl = mx * L2E;
            float s = 0.f;
#pragma unroll
            for (int n = 0; n < 32; ++n) {
                const int row = srq * 32 + ((n + scol) & 31);
                s += exp2f(fmaf((float)Tt[row * 136 + scol], L2E, -mxl));
            }
            float pmv = mxl, psv = s;
#pragma unroll
            for (int d = 1; d < 4; d <<= 1) {
                float om = __shfl_xor(pmv, d, 64);
                float os = __shfl_xor(psv, d, 64);
                float nm = fmaxf(pmv, om);
                psv = psv * exp2f(pmv - nm) + os * exp2f(om - nm);
                pmv = nm;
            }
            if (srq == 0) {
                const int part = (b * 4 + (m0 >> 8)) * 8 + (n0 >> 7);
                const int ml = mh * 128 + scol;
                Pm[(size_t)part * 256 + ml] = pmv;
                Ps[(size_t)part * 256 + ml] = psv;
            }
            if (mh == 0) WG_BARRIER();
        }
    }
}

// ---------------------------------------------------------------------------
// GEMM3: out[b][c][j] (f32) = n2[b](f32->f16 at staging) @ At[b]^T, with
// At[j][o] = exp2(Et[j][o]*log2e - Sc[b][o]) applied at B-staging.
// M=512, N=1024, K=1024. 256 blocks. (Unchanged from R10.)
__global__ __launch_bounds__(512) void gemm3_nt_out(const float* __restrict__ A,
                                                    const f16* __restrict__ Et,
                                                    const float* __restrict__ Sc,
                                                    float* __restrict__ C) {
    const int K = 1024;
    const int id = blockIdx.x;
    const int xcd = id & 7, loc = id >> 3;         // loc 0..31
    const int b = xcd * 2 + (loc >> 4);
    const int m0 = ((loc >> 3) & 1) * 256;
    const int n0 = (loc & 7) * 128;
    A += (size_t)b * 512 * K;
    Et += (size_t)b * 1024 * K;
    Sc += (size_t)b * 1024;
    C += (size_t)b * 512 * 1024;
    __shared__ __attribute__((aligned(16))) char SM[49152];
    const int tid = threadIdx.x, lane = tid & 63, wave = tid >> 6;
    const int col = lane & 15, quad = lane >> 4;
    const int wm = (wave & 3) * 64, wn = (wave >> 2) * 64;
    const int srow = tid >> 2, sslot = tid & 3;
    const int sOff = srow * 64 + ((sslot ^ ((srow >> 1) & 3)) * 16);
    const int swz16 = (quad ^ ((col >> 1) & 3)) * 16;
    const char* gA0 = (const char*)A + (size_t)(m0 + srow) * K * 4 + sslot * 32;
    const char* gA1 = gA0 + (size_t)128 * K * 4;
    const char* gB = (const char*)Et + (size_t)(n0 + srow) * K * 2 + sslot * 16;
    const float* gSp = Sc + sslot * 8;  // o-base of this thread's 8 staged elems
    f32x4 acc[4][4] = {};
    gemm_core_a32<32, true>(gA0, gA1, gB, gSp, SM, sOff, wm, wn, col, swz16, acc);

#pragma unroll
    for (int u = 0; u < 4; ++u)
#pragma unroll
        for (int v = 0; v < 4; ++v)
#pragma unroll
            for (int r = 0; r < 4; ++r)
                C[(size_t)(m0 + wm + u * 16 + quad * 4 + r) * 1024 + n0 + wn + v * 16 + col] =
                    acc[u][v][r];
}

// ---------------------------------------------------------------------------
extern "C" void kernel_launch(void* const* d_in, const int* in_sizes, int n_in,
                              void* d_out, int out_size, void* d_ws, size_t ws_size,
                              hipStream_t stream) {
    const float* n1 = (const float*)d_in[0];
    const float* n2 = (const float*)d_in[1];
    const float* Wc = (const float*)d_in[2];
    float* out = (float*)d_out;
    char* ws = (char*)d_ws;

    f16* n2t = (f16*)(ws);                   // [0,16M)   prep -> gemm2
    f16* Xt  = (f16*)(ws + (16u << 20));     // [16,32M)  gemm1 -> gemm2
    f16* Wf  = (f16*)(ws + (32u << 20));     // [32,34M)  prep -> gemm1 (dead before Et)
    f16* Et  = (f16*)(ws + (32u << 20));     // [32,64M)  gemm2 -> gemm3
    f16* n1f = (f16*)(ws + (64u << 20));     // [64,80M)  prep -> gemm1
    float* Pm = (float*)(ws + (80u << 20));  // 512 KiB
    float* Ps = (float*)(ws + (81u << 20));  // 512 KiB
    float* Sc = (float*)(ws + (82u << 20));  // 64 KiB (log2 units)

    prep<<<6656, dim3(256), 0, stream>>>(n1, Wc, n2, n1f, Wf, n2t);
    gemm1_nt_xt<<<256, dim3(512), 0, stream>>>(n1f, Wf, Xt);
    gemm2_nt_et<<<512, dim3(512), 0, stream>>>(Xt, n2t, Et, Pm, Ps);
    stats_combine<<<64, dim3(256), 0, stream>>>(Pm, Ps, Sc);
    gemm3_nt_out<<<256, dim3(512), 0, stream>>>(n2, Et, Sc, out);
}

// Round 12
// 197.495 us; speedup vs baseline: 1.0334x; 1.0149x over previous
//
#include <hip/hip_runtime.h>
#include <math.h>

// B=16, C=512, HW=1024.  Chain (per batch):
//   X  (C x HW)  = n1 @ W_c^T
//   E  (HW x HW) = X^T @ n2
//   A  = row-softmax(E)
//   out(C x HW)  = n2 @ A
//
// Round 19 = round 18 (200.4us, best) with the counted-vmcnt DMA core
// deepened from 2 to 3 LDS buffers (gemm1+gemm2):
//   steady-state wait = vmcnt(6): step kb's loads were issued at kb-3,
//   ~2 full compute-steps of cover (was ~1); 6 loads stay in flight
//   across each barrier pair. Tail decays 6->3->0 at compile time.
//   LDS 72KB: gemm1 1 block/CU (grid-capped) unchanged; gemm2 still
//   fits 2 blocks/CU (144KB <= 160KB) -- no occupancy loss.
// gemm3 (reg-staged a32 + exp fused at B-staging), prep, stats unchanged.
//
// Workspace (96 MiB, lifetime-aliased):
//   [0,16M):   n2t  f16 (prep -> gemm2)
//   [16,32M):  Xt   f16 (gemm1 -> gemm2)
//   [32,34M):  Wf   f16 (prep -> gemm1; overlaid by Et)
//   [32,64M):  Et   f16 (gemm2 -> gemm3)
//   [64,80M):  n1f  f16 (prep -> gemm1)
//   [80M+):    Pm/Ps partials, Sc stats

typedef _Float16 f16;
typedef _Float16 f16x8 __attribute__((ext_vector_type(8)));
typedef _Float16 f16x4 __attribute__((ext_vector_type(4)));
typedef float f32x4 __attribute__((ext_vector_type(4)));

#define L2E 1.442695040888963f

// Barrier with LDS-drain only (no vmcnt drain): prefetch survives it.
#define WG_BARRIER() asm volatile("s_waitcnt lgkmcnt(0)\ns_barrier" ::: "memory")

#define DMA16(g, l)                                                             \
    __builtin_amdgcn_global_load_lds(                                           \
        (const __attribute__((address_space(1))) void*)(g),                     \
        (__attribute__((address_space(3))) void*)(l), 16, 0, 0)

// f32 pair -> f16x8 (RTN)
__device__ __forceinline__ f16x8 cvt8(f32x4 lo, f32x4 hi) {
    f16x8 o;
#pragma unroll
    for (int i = 0; i < 4; ++i) { o[i] = (f16)lo[i]; o[4 + i] = (f16)hi[i]; }
    return o;
}

// exp-scale of a staged B vector: At = exp2(Et*log2e - Sc)
__device__ __forceinline__ f16x8 expb(f16x8 b, f32x4 cl, f32x4 ch) {
    f16x8 t;
#pragma unroll
    for (int i = 0; i < 4; ++i) t[i] = (f16)exp2f(fmaf((float)b[i], L2E, -cl[i]));
#pragma unroll
    for (int i = 0; i < 4; ++i) t[4 + i] = (f16)exp2f(fmaf((float)b[4 + i], L2E, -ch[i]));
    return t;
}

// ---------------------------------------------------------------------------
// Pre-pass. blockIdx.x:
//   [0,4096):    n1 -> n1f     [4096,4608): Wc -> Wf
//   [4608,6656): n2 -> n2t (transposed f16)
__global__ __launch_bounds__(256) void prep(const float* __restrict__ n1,
                                            const float* __restrict__ Wc,
                                            const float* __restrict__ n2,
                                            f16* __restrict__ n1f, f16* __restrict__ Wf,
                                            f16* __restrict__ n2t) {
    const int bid = blockIdx.x, tid = threadIdx.x;
    if (bid < 4608) {
        const float* s = (bid < 4096) ? n1 : Wc;
        f16* d = (bid < 4096) ? n1f : Wf;
        const size_t i = ((size_t)(bid < 4096 ? bid : bid - 4096) * 256 + tid) * 8;
        f32x4 a = *(const f32x4*)(s + i);
        f32x4 b = *(const f32x4*)(s + i + 4);
        *(f16x8*)(d + i) = cvt8(a, b);
        return;
    }
    const int id = bid - 4608;
    const int b = id >> 7;
    const int ry = (id & 127) >> 4;
    const int cx = id & 15;
    const float* S = n2 + (size_t)b * 512 * 1024;
    f16* Dt = n2t + (size_t)b * 1024 * 512;
    __shared__ f16 Ts[64 * 72];
    const int r0 = ry * 64, c0 = cx * 64;
    const int rr = tid >> 3, cc8 = (tid & 7) * 8;
#pragma unroll
    for (int h = 0; h < 2; ++h) {
        const int row = r0 + rr + 32 * h;
        const float* s = S + (size_t)row * 1024 + c0 + cc8;
        f32x4 a = *(const f32x4*)s, bq = *(const f32x4*)(s + 4);
        *(f16x8*)&Ts[(rr + 32 * h) * 72 + cc8] = cvt8(a, bq);
    }
    __syncthreads();
    const int j = tid >> 2, k16 = (tid & 3) * 16;
    f16* d = Dt + (size_t)(c0 + j) * 512 + r0 + k16;
    f16x8 o0, o1;
#pragma unroll
    for (int i = 0; i < 8; ++i) {
        o0[i] = Ts[(k16 + i) * 72 + j];
        o1[i] = Ts[(k16 + 8 + i) * 72 + j];
    }
    *(f16x8*)d = o0;
    *(f16x8*)(d + 8) = o1;
}

// ---------------------------------------------------------------------------
// stats_combine: per (b,o) fold 8 partials (log2 domain) ->
//   Sc[b][o] = log2(sum_h e^{E[o][h]}), log2 units.
__global__ __launch_bounds__(256) void stats_combine(const float* __restrict__ Pm,
                                                     const float* __restrict__ Ps,
                                                     float* __restrict__ Sc) {
    const int g = blockIdx.x * 256 + threadIdx.x;  // 16 * 1024
    const int b = g >> 10, o = g & 1023;
    const int mt = o >> 8, ml = o & 255;
    const float* pm = Pm + ((size_t)(b * 4 + mt) * 8) * 256 + ml;
    const float* ps = Ps + ((size_t)(b * 4 + mt) * 8) * 256 + ml;
    float M = -3.0e38f;
#pragma unroll
    for (int p = 0; p < 8; ++p) M = fmaxf(M, pm[p * 256]);
    float S = 0.f;
#pragma unroll
    for (int p = 0; p < 8; ++p) S += ps[p * 256] * exp2f(pm[p * 256] - M);
    Sc[g] = M + __log2f(S);
}

// ---------------------------------------------------------------------------
// 3-buffer counted-vmcnt DMA K-loop core. BM=256, BN=128, BK=32, 512 thr,
// 8 waves (4m x 2n), wave tile 64x64: 16 MFMA per 8 ds_read_b128 per step.
// LDS: A bufs @0/16384/32768 (16K each), B bufs @49152/57344/65536 (8K each).
// Per wave per step: 3 DMA16 (A lo rows, A hi rows, B), wave-uniform dest.
// Global source pre-swizzled (slot ls ^ ((r>>1)&3)); reads use swz16.
// Steady-state: wait vmcnt(6) (steps kb+1,kb+2 in flight); issue step kb+3
// into the buffer just read. Loads get ~2 full steps of cover.
template <int NS>
__device__ __forceinline__ void gemm_dmac(const char* sA0, const char* sA1,
                                          const char* sB, char* dA, char* dB,
                                          char* SM, int wm, int wn, int col,
                                          int swz16, f32x4 (&acc)[4][4]) {
#pragma unroll
    for (int s = 0; s < 3; ++s) {
        if (s < NS) {
            const int o = s * 64;
            char* da = dA + s * 16384;
            char* db = dB + s * 8192;
            DMA16(sA0 + o, da); DMA16(sA1 + o, da + 8192); DMA16(sB + o, db);
        }
    }
#pragma unroll
    for (int kb = 0; kb < NS; ++kb) {
        if (kb + 2 < NS)      asm volatile("s_waitcnt vmcnt(6)" ::: "memory");
        else if (kb + 1 < NS) asm volatile("s_waitcnt vmcnt(3)" ::: "memory");
        else                  asm volatile("s_waitcnt vmcnt(0)" ::: "memory");
        __builtin_amdgcn_s_barrier();
        asm volatile("" ::: "memory");
        const char* Ac = SM + (kb % 3) * 16384;
        const char* Bc = SM + 49152 + (kb % 3) * 8192;
        f16x8 fa[4], fb[4];
#pragma unroll
        for (int u = 0; u < 4; ++u)
            fa[u] = *(const f16x8*)(Ac + (wm + u * 16 + col) * 64 + swz16);
#pragma unroll
        for (int v = 0; v < 4; ++v)
            fb[v] = *(const f16x8*)(Bc + (wn + v * 16 + col) * 64 + swz16);
        asm volatile("s_waitcnt lgkmcnt(0)" ::: "memory");
        __builtin_amdgcn_s_barrier();
        asm volatile("" ::: "memory");
        if (kb + 3 < NS) {
            const int o = (kb + 3) * 64;
            char* da = dA + (kb % 3) * 16384;
            char* db = dB + (kb % 3) * 8192;
            DMA16(sA0 + o, da); DMA16(sA1 + o, da + 8192); DMA16(sB + o, db);
        }
#pragma unroll
        for (int u = 0; u < 4; ++u)
#pragma unroll
            for (int v = 0; v < 4; ++v)
                acc[u][v] = __builtin_amdgcn_mfma_f32_16x16x32_f16(fa[u], fb[v],
                                                                   acc[u][v], 0, 0, 0);
    }
}

// ---------------------------------------------------------------------------
// Reg-staged core with f32 A + EXPB (gemm3, unchanged).
template <int NS, bool EXPB>
__device__ __forceinline__ void gemm_core_a32(const char* gA0, const char* gA1,
                                              const char* gB, const float* gSp,
                                              char* SM, int sOff, int wm, int wn,
                                              int col, int swz16, f32x4 (&acc)[4][4]) {
    f32x4 c00, c01, c10, c11;
    f32x4 a00l = *(const f32x4*)gA0, a00h = *(const f32x4*)(gA0 + 16);
    f32x4 a01l = *(const f32x4*)gA1, a01h = *(const f32x4*)(gA1 + 16);
    f16x8 b0 = *(const f16x8*)gB;
    if (EXPB) { c00 = *(const f32x4*)gSp; c01 = *(const f32x4*)(gSp + 4); }
    {
        char* dA = SM + sOff;
        *(f16x8*)dA = cvt8(a00l, a00h);
        *(f16x8*)(dA + 8192) = cvt8(a01l, a01h);
        char* dB = SM + 32768 + sOff;
        *(f16x8*)dB = EXPB ? expb(b0, c00, c01) : b0;
    }
    f32x4 a10l = *(const f32x4*)(gA0 + 128), a10h = *(const f32x4*)(gA0 + 144);
    f32x4 a11l = *(const f32x4*)(gA1 + 128), a11h = *(const f32x4*)(gA1 + 144);
    f16x8 b1 = *(const f16x8*)(gB + 64);
    if (EXPB) { c10 = *(const f32x4*)(gSp + 32); c11 = *(const f32x4*)(gSp + 36); }
    a00l = *(const f32x4*)(gA0 + 256); a00h = *(const f32x4*)(gA0 + 272);
    a01l = *(const f32x4*)(gA1 + 256); a01h = *(const f32x4*)(gA1 + 272);
    b0 = *(const f16x8*)(gB + 128);
    if (EXPB) { c00 = *(const f32x4*)(gSp + 64); c01 = *(const f32x4*)(gSp + 68); }
    WG_BARRIER();
#pragma unroll
    for (int kb = 0; kb < NS; ++kb) {
        const char* Ac = SM + (kb & 1) * 16384;
        const char* Bc = SM + 32768 + (kb & 1) * 8192;
        f16x8 fa[4], fb[4];
#pragma unroll
        for (int u = 0; u < 4; ++u)
            fa[u] = *(const f16x8*)(Ac + (wm + u * 16 + col) * 64 + swz16);
#pragma unroll
        for (int v = 0; v < 4; ++v)
            fb[v] = *(const f16x8*)(Bc + (wn + v * 16 + col) * 64 + swz16);
#pragma unroll
        for (int u = 0; u < 4; ++u)
#pragma unroll
            for (int v = 0; v < 4; ++v)
                acc[u][v] = __builtin_amdgcn_mfma_f32_16x16x32_f16(fa[u], fb[v],
                                                                   acc[u][v], 0, 0, 0);
        if (kb + 1 < NS) {
            char* dA = SM + ((kb + 1) & 1) * 16384 + sOff;
            char* dB = SM + 32768 + ((kb + 1) & 1) * 8192 + sOff;
            if ((kb & 1) == 0) {
                *(f16x8*)dA = cvt8(a10l, a10h);
                *(f16x8*)(dA + 8192) = cvt8(a11l, a11h);
                *(f16x8*)dB = EXPB ? expb(b1, c10, c11) : b1;
                if (kb + 3 < NS) {
                    a10l = *(const f32x4*)(gA0 + (size_t)(kb + 3) * 128);
                    a10h = *(const f32x4*)(gA0 + (size_t)(kb + 3) * 128 + 16);
                    a11l = *(const f32x4*)(gA1 + (size_t)(kb + 3) * 128);
                    a11h = *(const f32x4*)(gA1 + (size_t)(kb + 3) * 128 + 16);
                    b1 = *(const f16x8*)(gB + (size_t)(kb + 3) * 64);
                    if (EXPB) {
                        c10 = *(const f32x4*)(gSp + (size_t)(kb + 3) * 32);
                        c11 = *(const f32x4*)(gSp + (size_t)(kb + 3) * 32 + 4);
                    }
                }
            } else {
                *(f16x8*)dA = cvt8(a00l, a00h);
                *(f16x8*)(dA + 8192) = cvt8(a01l, a01h);
                *(f16x8*)dB = EXPB ? expb(b0, c00, c01) : b0;
                if (kb + 3 < NS) {
                    a00l = *(const f32x4*)(gA0 + (size_t)(kb + 3) * 128);
                    a00h = *(const f32x4*)(gA0 + (size_t)(kb + 3) * 128 + 16);
                    a01l = *(const f32x4*)(gA1 + (size_t)(kb + 3) * 128);
                    a01h = *(const f32x4*)(gA1 + (size_t)(kb + 3) * 128 + 16);
                    b0 = *(const f16x8*)(gB + (size_t)(kb + 3) * 64);
                    if (EXPB) {
                        c00 = *(const f32x4*)(gSp + (size_t)(kb + 3) * 32);
                        c01 = *(const f32x4*)(gSp + (size_t)(kb + 3) * 32 + 4);
                    }
                }
            }
            WG_BARRIER();
        }
    }
}

// Transposed f16 epilogue: two m-half passes through Tt[128][136].
__device__ __forceinline__ void epilogue_tr(f32x4 (&acc)[4][4], char* SM, f16* dst0,
                                            int dstRow, int m0, int n0, int tid) {
    const int lane = tid & 63, wave = tid >> 6;
    const int col = lane & 15, quad = lane >> 4;
    const int wn = (wave >> 2) * 64;
    const int mh_w = (wave >> 1) & 1;
    const int wm_loc = (wave & 1) * 64;
    const int j = tid >> 2, seg = (tid & 3) * 32;
    WG_BARRIER();  // all frag reads of SM done before overwrite
    f16* Tt = (f16*)SM;
#pragma unroll
    for (int mh = 0; mh < 2; ++mh) {
        if (mh_w == mh) {
#pragma unroll
            for (int u = 0; u < 4; ++u)
#pragma unroll
                for (int v = 0; v < 4; ++v) {
                    f16x4 p;
#pragma unroll
                    for (int r = 0; r < 4; ++r) p[r] = (f16)acc[u][v][r];
                    *(f16x4*)&Tt[(wn + v * 16 + col) * 136 + wm_loc + u * 16 + quad * 4] = p;
                }
        }
        WG_BARRIER();
        f16* dst = dst0 + (size_t)(n0 + j) * dstRow + m0 + mh * 128 + seg;
#pragma unroll
        for (int c8 = 0; c8 < 32; c8 += 8)
            *(f16x8*)(dst + c8) = *(const f16x8*)&Tt[j * 136 + seg + c8];
        if (mh == 0) WG_BARRIER();
    }
}

// ---------------------------------------------------------------------------
// GEMM1: Xt[b][o][c] = (n1f[b] @ Wf^T)^T.  M=512, N=1024, K=1024. 256 blocks.
// 3-buffer counted-vmcnt DMA core.
__global__ __launch_bounds__(512) void gemm1_nt_xt(const f16* __restrict__ A,
                                                   const f16* __restrict__ Bw,
                                                   f16* __restrict__ Xt) {
    const int id = blockIdx.x;
    const int xcd = id & 7, loc = id >> 3;         // loc 0..31
    const int b = xcd * 2 + (loc >> 4);
    const int m0 = ((loc >> 3) & 1) * 256;
    const int n0 = (loc & 7) * 128;
    A += (size_t)b * 512 * 1024;
    Xt += (size_t)b * 1024 * 512;
    __shared__ __attribute__((aligned(16))) char SM[73728];
    const int tid = threadIdx.x, lane = tid & 63, wave = tid >> 6;
    const int col = lane & 15, quad = lane >> 4;
    const int wm = (wave & 3) * 64, wn = (wave >> 2) * 64;
    const int swz16 = (quad ^ ((col >> 1) & 3)) * 16;
    const int r = wave * 16 + (lane >> 2), ls = lane & 3;
    const int x = (r >> 1) & 3;
    const char* sA0 = (const char*)A + (size_t)(m0 + r) * 2048 + ((ls ^ x) * 16);
    const char* sA1 = sA0 + (size_t)128 * 2048;
    const char* sB  = (const char*)Bw + (size_t)(n0 + r) * 2048 + ((ls ^ x) * 16);
    char* dA = SM + wave * 1024;
    char* dB = SM + 49152 + wave * 1024;
    f32x4 acc[4][4] = {};
    gemm_dmac<32>(sA0, sA1, sB, dA, dB, SM, wm, wn, col, swz16, acc);
    epilogue_tr(acc, SM, Xt, 512, m0, n0, tid);
}

// ---------------------------------------------------------------------------
// GEMM2: Et[b][h][o] (f16) = (Xt[b] @ n2t[b]^T)^T.  M=1024, N=1024, K=512.
// 512 blocks. 3-buffer counted-vmcnt DMA core + lean Tt-based stats fusion.
__global__ __launch_bounds__(512) void gemm2_nt_et(const f16* __restrict__ A,
                                                   const f16* __restrict__ B,
                                                   f16* __restrict__ Et,
                                                   float* __restrict__ Pm,
                                                   float* __restrict__ Ps) {
    const int id = blockIdx.x;
    const int xcd = id & 7, loc = id >> 3;         // loc 0..63
    const int b = xcd * 2 + (loc >> 5);
    const int m0 = ((loc >> 3) & 3) * 256;
    const int n0 = (loc & 7) * 128;
    A += (size_t)b * 1024 * 512;
    B += (size_t)b * 1024 * 512;
    Et += (size_t)b * 1024 * 1024;
    __shared__ __attribute__((aligned(16))) char SM[73728];
    const int tid = threadIdx.x, lane = tid & 63, wave = tid >> 6;
    const int col = lane & 15, quad = lane >> 4;
    const int wm = (wave & 3) * 64, wn = (wave >> 2) * 64;
    const int swz16 = (quad ^ ((col >> 1) & 3)) * 16;
    const int r = wave * 16 + (lane >> 2), ls = lane & 3;
    const int x = (r >> 1) & 3;
    const char* sA0 = (const char*)A + (size_t)(m0 + r) * 1024 + ((ls ^ x) * 16);
    const char* sA1 = sA0 + (size_t)128 * 1024;
    const char* sB  = (const char*)B + (size_t)(n0 + r) * 1024 + ((ls ^ x) * 16);
    char* dA = SM + wave * 1024;
    char* dB = SM + 49152 + wave * 1024;
    f32x4 acc[4][4] = {};
    gemm_dmac<16>(sA0, sA1, sB, dA, dB, SM, wm, wn, col, swz16, acc);

    // ---- transposed epilogue + fused column-softmax stats from Tt.
    {
        const int wn_e = (wave >> 2) * 64;
        const int mh_w = (wave >> 1) & 1;
        const int wm_loc = (wave & 1) * 64;
        const int j = tid >> 2, seg = (tid & 3) * 32;
        const int scol = tid >> 2, srq = tid & 3;   // o-column, row-quarter
        WG_BARRIER();  // all frag reads of SM done before overwrite
        f16* Tt = (f16*)SM;
#pragma unroll
        for (int mh = 0; mh < 2; ++mh) {
            if (mh_w == mh) {
#pragma unroll
                for (int u = 0; u < 4; ++u)
#pragma unroll
                    for (int v = 0; v < 4; ++v) {
                        f16x4 p;
#pragma unroll
                        for (int r2 = 0; r2 < 4; ++r2) p[r2] = (f16)acc[u][v][r2];
                        *(f16x4*)&Tt[(wn_e + v * 16 + col) * 136 + wm_loc + u * 16 + quad * 4] = p;
                    }
            }
            WG_BARRIER();
            // coalesced Et rows
            f16* dst = Et + (size_t)(n0 + j) * 1024 + m0 + mh * 128 + seg;
#pragma unroll
            for (int c8 = 0; c8 < 32; c8 += 8)
                *(f16x8*)(dst + c8) = *(const f16x8*)&Tt[j * 136 + seg + c8];
            // stats: o = m0 + mh*128 + scol; rows srq*32..+32 (rotated reads).
            float mx = -3.0e38f;
#pragma unroll
            for (int n = 0; n < 32; ++n) {
                const int row = srq * 32 + ((n + scol) & 31);
                mx = fmaxf(mx, (float)Tt[row * 136 + scol]);
            }
            const float mxl = mx * L2E;
            float s = 0.f;
#pragma unroll
            for (int n = 0; n < 32; ++n) {
                const int row = srq * 32 + ((n + scol) & 31);
                s += exp2f(fmaf((float)Tt[row * 136 + scol], L2E, -mxl));
            }
            float pmv = mxl, psv = s;
#pragma unroll
            for (int d = 1; d < 4; d <<= 1) {
                float om = __shfl_xor(pmv, d, 64);
                float os = __shfl_xor(psv, d, 64);
                float nm = fmaxf(pmv, om);
                psv = psv * exp2f(pmv - nm) + os * exp2f(om - nm);
                pmv = nm;
            }
            if (srq == 0) {
                const int part = (b * 4 + (m0 >> 8)) * 8 + (n0 >> 7);
                const int ml = mh * 128 + scol;
                Pm[(size_t)part * 256 + ml] = pmv;
                Ps[(size_t)part * 256 + ml] = psv;
            }
            if (mh == 0) WG_BARRIER();
        }
    }
}

// ---------------------------------------------------------------------------
// GEMM3: out[b][c][j] (f32) = n2[b](f32->f16 at staging) @ At[b]^T, with
// At[j][o] = exp2(Et[j][o]*log2e - Sc[b][o]) applied at B-staging.
// M=512, N=1024, K=1024. 256 blocks. (Unchanged.)
__global__ __launch_bounds__(512) void gemm3_nt_out(const float* __restrict__ A,
                                                    const f16* __restrict__ Et,
                                                    const float* __restrict__ Sc,
                                                    float* __restrict__ C) {
    const int K = 1024;
    const int id = blockIdx.x;
    const int xcd = id & 7, loc = id >> 3;         // loc 0..31
    const int b = xcd * 2 + (loc >> 4);
    const int m0 = ((loc >> 3) & 1) * 256;
    const int n0 = (loc & 7) * 128;
    A += (size_t)b * 512 * K;
    Et += (size_t)b * 1024 * K;
    Sc += (size_t)b * 1024;
    C += (size_t)b * 512 * 1024;
    __shared__ __attribute__((aligned(16))) char SM[49152];
    const int tid = threadIdx.x, lane = tid & 63, wave = tid >> 6;
    const int col = lane & 15, quad = lane >> 4;
    const int wm = (wave & 3) * 64, wn = (wave >> 2) * 64;
    const int srow = tid >> 2, sslot = tid & 3;
    const int sOff = srow * 64 + ((sslot ^ ((srow >> 1) & 3)) * 16);
    const int swz16 = (quad ^ ((col >> 1) & 3)) * 16;
    const char* gA0 = (const char*)A + (size_t)(m0 + srow) * K * 4 + sslot * 32;
    const char* gA1 = gA0 + (size_t)128 * K * 4;
    const char* gB = (const char*)Et + (size_t)(n0 + srow) * K * 2 + sslot * 16;
    const float* gSp = Sc + sslot * 8;  // o-base of this thread's 8 staged elems
    f32x4 acc[4][4] = {};
    gemm_core_a32<32, true>(gA0, gA1, gB, gSp, SM, sOff, wm, wn, col, swz16, acc);

#pragma unroll
    for (int u = 0; u < 4; ++u)
#pragma unroll
        for (int v = 0; v < 4; ++v)
#pragma unroll
            for (int r = 0; r < 4; ++r)
                C[(size_t)(m0 + wm + u * 16 + quad * 4 + r) * 1024 + n0 + wn + v * 16 + col] =
                    acc[u][v][r];
}

// ---------------------------------------------------------------------------
extern "C" void kernel_launch(void* const* d_in, const int* in_sizes, int n_in,
                              void* d_out, int out_size, void* d_ws, size_t ws_size,
                              hipStream_t stream) {
    const float* n1 = (const float*)d_in[0];
    const float* n2 = (const float*)d_in[1];
    const float* Wc = (const float*)d_in[2];
    float* out = (float*)d_out;
    char* ws = (char*)d_ws;

    f16* n2t = (f16*)(ws);                   // [0,16M)   prep -> gemm2
    f16* Xt  = (f16*)(ws + (16u << 20));     // [16,32M)  gemm1 -> gemm2
    f16* Wf  = (f16*)(ws + (32u << 20));     // [32,34M)  prep -> gemm1 (dead before Et)
    f16* Et  = (f16*)(ws + (32u << 20));     // [32,64M)  gemm2 -> gemm3
    f16* n1f = (f16*)(ws + (64u << 20));     // [64,80M)  prep -> gemm1
    float* Pm = (float*)(ws + (80u << 20));  // 512 KiB
    float* Ps = (float*)(ws + (81u << 20));  // 512 KiB
    float* Sc = (float*)(ws + (82u << 20));  // 64 KiB (log2 units)

    prep<<<6656, dim3(256), 0, stream>>>(n1, Wc, n2, n1f, Wf, n2t);
    gemm1_nt_xt<<<256, dim3(512), 0, stream>>>(n1f, Wf, Xt);
    gemm2_nt_et<<<512, dim3(512), 0, stream>>>(Xt, n2t, Et, Pm, Ps);
    stats_combine<<<64, dim3(256), 0, stream>>>(Pm, Ps, Sc);
    gemm3_nt_out<<<256, dim3(512), 0, stream>>>(n2, Et, Sc, out);
}

// Round 13
// 195.399 us; speedup vs baseline: 1.0444x; 1.0107x over previous
//
#include <hip/hip_runtime.h>
#include <math.h>

// B=16, C=512, HW=1024.  Chain (per batch):
//   X  (C x HW)  = n1 @ W_c^T
//   E  (HW x HW) = X^T @ n2
//   A  = row-softmax(E)
//   out(C x HW)  = n2 @ A
//
// Round 20 = round 19 (197.5us, best) + gemm3 ported to the counted-vmcnt
// DMA core with an in-loop LDS exp phase:
//  - A = n2f f16 (restored in prep) via DMA; B = raw Et via DMA into Braw.
//  - Step phase 1 (after vmcnt(6)+barrier): each thread reads its OWN 16B
//    raw slot, applies exp2(fma(raw,L2E,-Sc)) (Sc staged once in LDS, 4KB,
//    per-thread-constant index + kb*32), writes to 2-deep Bexp; A-fragment
//    reads happen in the same phase. Phase 2 (after lgkmcnt(0)+barrier,
//    which also frees Braw[kb%3] for the kb+3 DMA): B-fragment reads from
//    Bexp + 16 MFMA. Still 2 barriers/step, vmcnt(6/3/0), 3 DMA/step.
//  - Math bit-identical to R19's expb (same operands/order).
// gemm1/gemm2 (3-buf counted DMA), stats fusion, stats_combine unchanged.
//
// Workspace (96 MiB, lifetime-aliased):
//   [0,16M):   n2t  f16 (prep -> gemm2)
//   [16,32M):  Xt   f16 (gemm1 -> gemm2)
//   [32,34M):  Wf   f16 (prep -> gemm1; overlaid by Et)
//   [32,64M):  Et   f16 (gemm2 -> gemm3)
//   [64,80M):  n1f  f16 (prep -> gemm1); Pm/Ps/Sc overlay after gemm1
//   [80,96M):  n2f  f16 (prep -> gemm3)

typedef _Float16 f16;
typedef _Float16 f16x8 __attribute__((ext_vector_type(8)));
typedef _Float16 f16x4 __attribute__((ext_vector_type(4)));
typedef float f32x4 __attribute__((ext_vector_type(4)));

#define L2E 1.442695040888963f

// Barrier with LDS-drain only (no vmcnt drain): prefetch survives it.
#define WG_BARRIER() asm volatile("s_waitcnt lgkmcnt(0)\ns_barrier" ::: "memory")

#define DMA16(g, l)                                                             \
    __builtin_amdgcn_global_load_lds(                                           \
        (const __attribute__((address_space(1))) void*)(g),                     \
        (__attribute__((address_space(3))) void*)(l), 16, 0, 0)

// f32 pair -> f16x8 (RTN)
__device__ __forceinline__ f16x8 cvt8(f32x4 lo, f32x4 hi) {
    f16x8 o;
#pragma unroll
    for (int i = 0; i < 4; ++i) { o[i] = (f16)lo[i]; o[4 + i] = (f16)hi[i]; }
    return o;
}

// exp-scale of a staged B vector: At = exp2(Et*log2e - Sc)
__device__ __forceinline__ f16x8 expb(f16x8 b, f32x4 cl, f32x4 ch) {
    f16x8 t;
#pragma unroll
    for (int i = 0; i < 4; ++i) t[i] = (f16)exp2f(fmaf((float)b[i], L2E, -cl[i]));
#pragma unroll
    for (int i = 0; i < 4; ++i) t[4 + i] = (f16)exp2f(fmaf((float)b[4 + i], L2E, -ch[i]));
    return t;
}

// ---------------------------------------------------------------------------
// Pre-pass. blockIdx.x:
//   [0,4096):    n1 -> n1f     [4096,4608): Wc -> Wf
//   [4608,6656): n2 -> n2f (natural) + n2t (transposed)
__global__ __launch_bounds__(256) void prep(const float* __restrict__ n1,
                                            const float* __restrict__ Wc,
                                            const float* __restrict__ n2,
                                            f16* __restrict__ n1f, f16* __restrict__ Wf,
                                            f16* __restrict__ n2f, f16* __restrict__ n2t) {
    const int bid = blockIdx.x, tid = threadIdx.x;
    if (bid < 4608) {
        const float* s = (bid < 4096) ? n1 : Wc;
        f16* d = (bid < 4096) ? n1f : Wf;
        const size_t i = ((size_t)(bid < 4096 ? bid : bid - 4096) * 256 + tid) * 8;
        f32x4 a = *(const f32x4*)(s + i);
        f32x4 b = *(const f32x4*)(s + i + 4);
        *(f16x8*)(d + i) = cvt8(a, b);
        return;
    }
    const int id = bid - 4608;
    const int b = id >> 7;
    const int ry = (id & 127) >> 4;
    const int cx = id & 15;
    const float* S = n2 + (size_t)b * 512 * 1024;
    f16* Dn = n2f + (size_t)b * 512 * 1024;
    f16* Dt = n2t + (size_t)b * 1024 * 512;
    __shared__ f16 Ts[64 * 72];
    const int r0 = ry * 64, c0 = cx * 64;
    const int rr = tid >> 3, cc8 = (tid & 7) * 8;
#pragma unroll
    for (int h = 0; h < 2; ++h) {
        const int row = r0 + rr + 32 * h;
        const float* s = S + (size_t)row * 1024 + c0 + cc8;
        f32x4 a = *(const f32x4*)s, bq = *(const f32x4*)(s + 4);
        f16x8 o = cvt8(a, bq);
        *(f16x8*)&Ts[(rr + 32 * h) * 72 + cc8] = o;
        *(f16x8*)(Dn + (size_t)row * 1024 + c0 + cc8) = o;
    }
    __syncthreads();
    const int j = tid >> 2, k16 = (tid & 3) * 16;
    f16* d = Dt + (size_t)(c0 + j) * 512 + r0 + k16;
    f16x8 o0, o1;
#pragma unroll
    for (int i = 0; i < 8; ++i) {
        o0[i] = Ts[(k16 + i) * 72 + j];
        o1[i] = Ts[(k16 + 8 + i) * 72 + j];
    }
    *(f16x8*)d = o0;
    *(f16x8*)(d + 8) = o1;
}

// ---------------------------------------------------------------------------
// stats_combine: per (b,o) fold 8 partials (log2 domain) ->
//   Sc[b][o] = log2(sum_h e^{E[o][h]}), log2 units.
__global__ __launch_bounds__(256) void stats_combine(const float* __restrict__ Pm,
                                                     const float* __restrict__ Ps,
                                                     float* __restrict__ Sc) {
    const int g = blockIdx.x * 256 + threadIdx.x;  // 16 * 1024
    const int b = g >> 10, o = g & 1023;
    const int mt = o >> 8, ml = o & 255;
    const float* pm = Pm + ((size_t)(b * 4 + mt) * 8) * 256 + ml;
    const float* ps = Ps + ((size_t)(b * 4 + mt) * 8) * 256 + ml;
    float M = -3.0e38f;
#pragma unroll
    for (int p = 0; p < 8; ++p) M = fmaxf(M, pm[p * 256]);
    float S = 0.f;
#pragma unroll
    for (int p = 0; p < 8; ++p) S += ps[p * 256] * exp2f(pm[p * 256] - M);
    Sc[g] = M + __log2f(S);
}

// ---------------------------------------------------------------------------
// 3-buffer counted-vmcnt DMA K-loop core (gemm1/gemm2, unchanged from R19).
// LDS: A bufs @0/16384/32768 (16K), B bufs @49152/57344/65536 (8K).
template <int NS>
__device__ __forceinline__ void gemm_dmac(const char* sA0, const char* sA1,
                                          const char* sB, char* dA, char* dB,
                                          char* SM, int wm, int wn, int col,
                                          int swz16, f32x4 (&acc)[4][4]) {
#pragma unroll
    for (int s = 0; s < 3; ++s) {
        if (s < NS) {
            const int o = s * 64;
            char* da = dA + s * 16384;
            char* db = dB + s * 8192;
            DMA16(sA0 + o, da); DMA16(sA1 + o, da + 8192); DMA16(sB + o, db);
        }
    }
#pragma unroll
    for (int kb = 0; kb < NS; ++kb) {
        if (kb + 2 < NS)      asm volatile("s_waitcnt vmcnt(6)" ::: "memory");
        else if (kb + 1 < NS) asm volatile("s_waitcnt vmcnt(3)" ::: "memory");
        else                  asm volatile("s_waitcnt vmcnt(0)" ::: "memory");
        __builtin_amdgcn_s_barrier();
        asm volatile("" ::: "memory");
        const char* Ac = SM + (kb % 3) * 16384;
        const char* Bc = SM + 49152 + (kb % 3) * 8192;
        f16x8 fa[4], fb[4];
#pragma unroll
        for (int u = 0; u < 4; ++u)
            fa[u] = *(const f16x8*)(Ac + (wm + u * 16 + col) * 64 + swz16);
#pragma unroll
        for (int v = 0; v < 4; ++v)
            fb[v] = *(const f16x8*)(Bc + (wn + v * 16 + col) * 64 + swz16);
        asm volatile("s_waitcnt lgkmcnt(0)" ::: "memory");
        __builtin_amdgcn_s_barrier();
        asm volatile("" ::: "memory");
        if (kb + 3 < NS) {
            const int o = (kb + 3) * 64;
            char* da = dA + (kb % 3) * 16384;
            char* db = dB + (kb % 3) * 8192;
            DMA16(sA0 + o, da); DMA16(sA1 + o, da + 8192); DMA16(sB + o, db);
        }
#pragma unroll
        for (int u = 0; u < 4; ++u)
#pragma unroll
            for (int v = 0; v < 4; ++v)
                acc[u][v] = __builtin_amdgcn_mfma_f32_16x16x32_f16(fa[u], fb[v],
                                                                   acc[u][v], 0, 0, 0);
    }
}

// ---------------------------------------------------------------------------
// gemm3 core: counted-vmcnt DMA + in-loop LDS exp phase.
// LDS: A @0/16384/32768 (48K) ; Braw @49152/57344/65536 (24K) ;
//      Bexp @73728/81920 (16K) ; ScL @90112 (4K).  Total 94208 B.
// Per step: phase1 = own-slot raw read + Sc read + exp + Bexp write +
// A-frag reads; bar; DMA kb+3; phase2 = B-frag reads + 16 MFMA.
template <int NS>
__device__ __forceinline__ void gemm_dmac_exp(const char* sA0, const char* sA1,
                                              const char* sB, char* dA, char* dB,
                                              char* SM, int wm, int wn, int col,
                                              int swz16, int slotOff, int kloc,
                                              f32x4 (&acc)[4][4]) {
    const float* scL = (const float*)(SM + 90112);
#pragma unroll
    for (int s = 0; s < 3; ++s) {
        if (s < NS) {
            const int o = s * 64;
            char* da = dA + s * 16384;
            char* db = dB + s * 8192;
            DMA16(sA0 + o, da); DMA16(sA1 + o, da + 8192); DMA16(sB + o, db);
        }
    }
#pragma unroll
    for (int kb = 0; kb < NS; ++kb) {
        if (kb + 2 < NS)      asm volatile("s_waitcnt vmcnt(6)" ::: "memory");
        else if (kb + 1 < NS) asm volatile("s_waitcnt vmcnt(3)" ::: "memory");
        else                  asm volatile("s_waitcnt vmcnt(0)" ::: "memory");
        __builtin_amdgcn_s_barrier();
        asm volatile("" ::: "memory");
        const char* Ac = SM + (kb % 3) * 16384;
        const char* Braw = SM + 49152 + (kb % 3) * 8192;
        char* Bexp = SM + 73728 + (kb & 1) * 8192;
        // phase 1: A-frags + own-slot exp
        f16x8 fa[4];
#pragma unroll
        for (int u = 0; u < 4; ++u)
            fa[u] = *(const f16x8*)(Ac + (wm + u * 16 + col) * 64 + swz16);
        {
            f16x8 raw = *(const f16x8*)(Braw + slotOff);
            f32x4 s0 = *(const f32x4*)(scL + kb * 32 + kloc);
            f32x4 s1 = *(const f32x4*)(scL + kb * 32 + kloc + 4);
            *(f16x8*)(Bexp + slotOff) = expb(raw, s0, s1);
        }
        asm volatile("s_waitcnt lgkmcnt(0)" ::: "memory");
        __builtin_amdgcn_s_barrier();
        asm volatile("" ::: "memory");
        if (kb + 3 < NS) {
            const int o = (kb + 3) * 64;
            char* da = dA + (kb % 3) * 16384;
            char* db = dB + (kb % 3) * 8192;
            DMA16(sA0 + o, da); DMA16(sA1 + o, da + 8192); DMA16(sB + o, db);
        }
        // phase 2: B-frags from Bexp + MFMA
        f16x8 fb[4];
#pragma unroll
        for (int v = 0; v < 4; ++v)
            fb[v] = *(const f16x8*)(Bexp + (wn + v * 16 + col) * 64 + swz16);
#pragma unroll
        for (int u = 0; u < 4; ++u)
#pragma unroll
            for (int v = 0; v < 4; ++v)
                acc[u][v] = __builtin_amdgcn_mfma_f32_16x16x32_f16(fa[u], fb[v],
                                                                   acc[u][v], 0, 0, 0);
    }
}

// Transposed f16 epilogue: two m-half passes through Tt[128][136].
__device__ __forceinline__ void epilogue_tr(f32x4 (&acc)[4][4], char* SM, f16* dst0,
                                            int dstRow, int m0, int n0, int tid) {
    const int lane = tid & 63, wave = tid >> 6;
    const int col = lane & 15, quad = lane >> 4;
    const int wn = (wave >> 2) * 64;
    const int mh_w = (wave >> 1) & 1;
    const int wm_loc = (wave & 1) * 64;
    const int j = tid >> 2, seg = (tid & 3) * 32;
    WG_BARRIER();  // all frag reads of SM done before overwrite
    f16* Tt = (f16*)SM;
#pragma unroll
    for (int mh = 0; mh < 2; ++mh) {
        if (mh_w == mh) {
#pragma unroll
            for (int u = 0; u < 4; ++u)
#pragma unroll
                for (int v = 0; v < 4; ++v) {
                    f16x4 p;
#pragma unroll
                    for (int r = 0; r < 4; ++r) p[r] = (f16)acc[u][v][r];
                    *(f16x4*)&Tt[(wn + v * 16 + col) * 136 + wm_loc + u * 16 + quad * 4] = p;
                }
        }
        WG_BARRIER();
        f16* dst = dst0 + (size_t)(n0 + j) * dstRow + m0 + mh * 128 + seg;
#pragma unroll
        for (int c8 = 0; c8 < 32; c8 += 8)
            *(f16x8*)(dst + c8) = *(const f16x8*)&Tt[j * 136 + seg + c8];
        if (mh == 0) WG_BARRIER();
    }
}

// ---------------------------------------------------------------------------
// GEMM1: Xt[b][o][c] = (n1f[b] @ Wf^T)^T.  M=512, N=1024, K=1024. 256 blocks.
__global__ __launch_bounds__(512) void gemm1_nt_xt(const f16* __restrict__ A,
                                                   const f16* __restrict__ Bw,
                                                   f16* __restrict__ Xt) {
    const int id = blockIdx.x;
    const int xcd = id & 7, loc = id >> 3;         // loc 0..31
    const int b = xcd * 2 + (loc >> 4);
    const int m0 = ((loc >> 3) & 1) * 256;
    const int n0 = (loc & 7) * 128;
    A += (size_t)b * 512 * 1024;
    Xt += (size_t)b * 1024 * 512;
    __shared__ __attribute__((aligned(16))) char SM[73728];
    const int tid = threadIdx.x, lane = tid & 63, wave = tid >> 6;
    const int col = lane & 15, quad = lane >> 4;
    const int wm = (wave & 3) * 64, wn = (wave >> 2) * 64;
    const int swz16 = (quad ^ ((col >> 1) & 3)) * 16;
    const int r = wave * 16 + (lane >> 2), ls = lane & 3;
    const int x = (r >> 1) & 3;
    const char* sA0 = (const char*)A + (size_t)(m0 + r) * 2048 + ((ls ^ x) * 16);
    const char* sA1 = sA0 + (size_t)128 * 2048;
    const char* sB  = (const char*)Bw + (size_t)(n0 + r) * 2048 + ((ls ^ x) * 16);
    char* dA = SM + wave * 1024;
    char* dB = SM + 49152 + wave * 1024;
    f32x4 acc[4][4] = {};
    gemm_dmac<32>(sA0, sA1, sB, dA, dB, SM, wm, wn, col, swz16, acc);
    epilogue_tr(acc, SM, Xt, 512, m0, n0, tid);
}

// ---------------------------------------------------------------------------
// GEMM2: Et[b][h][o] (f16) = (Xt[b] @ n2t[b]^T)^T.  M=1024, N=1024, K=512.
// 512 blocks. Counted DMA core + lean Tt-based stats fusion.
__global__ __launch_bounds__(512) void gemm2_nt_et(const f16* __restrict__ A,
                                                   const f16* __restrict__ B,
                                                   f16* __restrict__ Et,
                                                   float* __restrict__ Pm,
                                                   float* __restrict__ Ps) {
    const int id = blockIdx.x;
    const int xcd = id & 7, loc = id >> 3;         // loc 0..63
    const int b = xcd * 2 + (loc >> 5);
    const int m0 = ((loc >> 3) & 3) * 256;
    const int n0 = (loc & 7) * 128;
    A += (size_t)b * 1024 * 512;
    B += (size_t)b * 1024 * 512;
    Et += (size_t)b * 1024 * 1024;
    __shared__ __attribute__((aligned(16))) char SM[73728];
    const int tid = threadIdx.x, lane = tid & 63, wave = tid >> 6;
    const int col = lane & 15, quad = lane >> 4;
    const int wm = (wave & 3) * 64, wn = (wave >> 2) * 64;
    const int swz16 = (quad ^ ((col >> 1) & 3)) * 16;
    const int r = wave * 16 + (lane >> 2), ls = lane & 3;
    const int x = (r >> 1) & 3;
    const char* sA0 = (const char*)A + (size_t)(m0 + r) * 1024 + ((ls ^ x) * 16);
    const char* sA1 = sA0 + (size_t)128 * 1024;
    const char* sB  = (const char*)B + (size_t)(n0 + r) * 1024 + ((ls ^ x) * 16);
    char* dA = SM + wave * 1024;
    char* dB = SM + 49152 + wave * 1024;
    f32x4 acc[4][4] = {};
    gemm_dmac<16>(sA0, sA1, sB, dA, dB, SM, wm, wn, col, swz16, acc);

    // ---- transposed epilogue + fused column-softmax stats from Tt.
    {
        const int wn_e = (wave >> 2) * 64;
        const int mh_w = (wave >> 1) & 1;
        const int wm_loc = (wave & 1) * 64;
        const int j = tid >> 2, seg = (tid & 3) * 32;
        const int scol = tid >> 2, srq = tid & 3;   // o-column, row-quarter
        WG_BARRIER();  // all frag reads of SM done before overwrite
        f16* Tt = (f16*)SM;
#pragma unroll
        for (int mh = 0; mh < 2; ++mh) {
            if (mh_w == mh) {
#pragma unroll
                for (int u = 0; u < 4; ++u)
#pragma unroll
                    for (int v = 0; v < 4; ++v) {
                        f16x4 p;
#pragma unroll
                        for (int r2 = 0; r2 < 4; ++r2) p[r2] = (f16)acc[u][v][r2];
                        *(f16x4*)&Tt[(wn_e + v * 16 + col) * 136 + wm_loc + u * 16 + quad * 4] = p;
                    }
            }
            WG_BARRIER();
            f16* dst = Et + (size_t)(n0 + j) * 1024 + m0 + mh * 128 + seg;
#pragma unroll
            for (int c8 = 0; c8 < 32; c8 += 8)
                *(f16x8*)(dst + c8) = *(const f16x8*)&Tt[j * 136 + seg + c8];
            float mx = -3.0e38f;
#pragma unroll
            for (int n = 0; n < 32; ++n) {
                const int row = srq * 32 + ((n + scol) & 31);
                mx = fmaxf(mx, (float)Tt[row * 136 + scol]);
            }
            const float mxl = mx * L2E;
            float s = 0.f;
#pragma unroll
            for (int n = 0; n < 32; ++n) {
                const int row = srq * 32 + ((n + scol) & 31);
                s += exp2f(fmaf((float)Tt[row * 136 + scol], L2E, -mxl));
            }
            float pmv = mxl, psv = s;
#pragma unroll
            for (int d = 1; d < 4; d <<= 1) {
                float om = __shfl_xor(pmv, d, 64);
                float os = __shfl_xor(psv, d, 64);
                float nm = fmaxf(pmv, om);
                psv = psv * exp2f(pmv - nm) + os * exp2f(om - nm);
                pmv = nm;
            }
            if (srq == 0) {
                const int part = (b * 4 + (m0 >> 8)) * 8 + (n0 >> 7);
                const int ml = mh * 128 + scol;
                Pm[(size_t)part * 256 + ml] = pmv;
                Ps[(size_t)part * 256 + ml] = psv;
            }
            if (mh == 0) WG_BARRIER();
        }
    }
}

// ---------------------------------------------------------------------------
// GEMM3: out[b][c][j] (f32) = n2f[b] @ At[b]^T with At[j][o] =
// exp2(Et[j][o]*log2e - Sc[b][o]) computed in the in-loop LDS exp phase.
// M=512, N=1024, K=1024. 256 blocks. Counted-vmcnt DMA core.
__global__ __launch_bounds__(512) void gemm3_nt_out(const f16* __restrict__ A,
                                                    const f16* __restrict__ Et,
                                                    const float* __restrict__ Sc,
                                                    float* __restrict__ C) {
    const int id = blockIdx.x;
    const int xcd = id & 7, loc = id >> 3;         // loc 0..31
    const int b = xcd * 2 + (loc >> 4);
    const int m0 = ((loc >> 3) & 1) * 256;
    const int n0 = (loc & 7) * 128;
    A += (size_t)b * 512 * 1024;
    Et += (size_t)b * 1024 * 1024;
    Sc += (size_t)b * 1024;
    C += (size_t)b * 512 * 1024;
    __shared__ __attribute__((aligned(16))) char SM[94208];
    const int tid = threadIdx.x, lane = tid & 63, wave = tid >> 6;
    const int col = lane & 15, quad = lane >> 4;
    const int wm = (wave & 3) * 64, wn = (wave >> 2) * 64;
    const int swz16 = (quad ^ ((col >> 1) & 3)) * 16;
    const int r = wave * 16 + (lane >> 2), ls = lane & 3;
    const int x = (r >> 1) & 3;
    const char* sA0 = (const char*)A + (size_t)(m0 + r) * 2048 + ((ls ^ x) * 16);
    const char* sA1 = sA0 + (size_t)128 * 2048;
    const char* sB  = (const char*)Et + (size_t)(n0 + r) * 2048 + ((ls ^ x) * 16);
    char* dA = SM + wave * 1024;
    char* dB = SM + 49152 + wave * 1024;
    const int slotOff = r * 64 + ls * 16;       // own physical B slot
    const int kloc = (ls ^ x) * 8;              // k-elem base within BK=32

    // Stage Sc[0..1024) into LDS once (4 KB @ 90112).
    {
        float* scL = (float*)(SM + 90112);
        if (tid < 256) {
            f32x4 v = *(const f32x4*)(Sc + tid * 4);
            *(f32x4*)(scL + tid * 4) = v;
        }
        WG_BARRIER();
    }

    f32x4 acc[4][4] = {};
    gemm_dmac_exp<32>(sA0, sA1, sB, dA, dB, SM, wm, wn, col, swz16,
                      slotOff, kloc, acc);

#pragma unroll
    for (int u = 0; u < 4; ++u)
#pragma unroll
        for (int v = 0; v < 4; ++v)
#pragma unroll
            for (int r2 = 0; r2 < 4; ++r2)
                C[(size_t)(m0 + wm + u * 16 + quad * 4 + r2) * 1024 + n0 + wn + v * 16 + col] =
                    acc[u][v][r2];
}

// ---------------------------------------------------------------------------
extern "C" void kernel_launch(void* const* d_in, const int* in_sizes, int n_in,
                              void* d_out, int out_size, void* d_ws, size_t ws_size,
                              hipStream_t stream) {
    const float* n1 = (const float*)d_in[0];
    const float* n2 = (const float*)d_in[1];
    const float* Wc = (const float*)d_in[2];
    float* out = (float*)d_out;
    char* ws = (char*)d_ws;

    f16* n2t = (f16*)(ws);                   // [0,16M)   prep -> gemm2
    f16* Xt  = (f16*)(ws + (16u << 20));     // [16,32M)  gemm1 -> gemm2
    f16* Wf  = (f16*)(ws + (32u << 20));     // [32,34M)  prep -> gemm1 (dead before Et)
    f16* Et  = (f16*)(ws + (32u << 20));     // [32,64M)  gemm2 -> gemm3
    f16* n1f = (f16*)(ws + (64u << 20));     // [64,80M)  prep -> gemm1 (dead after)
    f16* n2f = (f16*)(ws + (80u << 20));     // [80,96M)  prep -> gemm3
    float* Pm = (float*)(ws + (64u << 20));  // 512 KiB, over dead n1f
    float* Ps = (float*)(ws + (65u << 20));  // 512 KiB
    float* Sc = (float*)(ws + (66u << 20));  // 64 KiB (log2 units)

    prep<<<6656, dim3(256), 0, stream>>>(n1, Wc, n2, n1f, Wf, n2f, n2t);
    gemm1_nt_xt<<<256, dim3(512), 0, stream>>>(n1f, Wf, Xt);
    gemm2_nt_et<<<512, dim3(512), 0, stream>>>(Xt, n2t, Et, Pm, Ps);
    stats_combine<<<64, dim3(256), 0, stream>>>(Pm, Ps, Sc);
    gemm3_nt_out<<<256, dim3(512), 0, stream>>>(n2f, Et, Sc, out);
}